// Round 6
// baseline (1139.740 us; speedup 1.0000x reference)
//
#include <hip/hip_runtime.h>

#define N_NODES 100000
#define NPAD    100032      // multiple of 64 for unguarded GEMM tiles
#define NBLK    1563        // NPAD/64
#define NEDGE   800000
#define NGRP    128
#define NSLOT   32          // mirrored stat-accumulator slots (atomic contention /32)
#define EPS     1e-5f

typedef unsigned int   u32;
typedef unsigned short u16;
typedef short bf16x8 __attribute__((ext_vector_type(8)));
typedef float f32x4  __attribute__((ext_vector_type(4)));

__device__ __forceinline__ float bf2f(u32 u){ return __uint_as_float(u << 16); }
__device__ __forceinline__ u16 f2bf(float f){
  u32 x = __float_as_uint(f);
  x += 0x7fffu + ((x >> 16) & 1u);      // round-to-nearest-even
  return (u16)(x >> 16);
}

// ---------------- preprocessing ----------------
__global__ void k_init(float* deg, int* cnt, int* fill, float* gbuf){
  int i = blockIdx.x * 256 + threadIdx.x;
  if (i < NPAD){ deg[i] = 1.0f; cnt[i] = 0; fill[i] = 0; }   // deg starts at 1 (self-loop)
  if (i < 4 * NGRP * 128) gbuf[i] = 0.f;
}

__global__ void k_deg(const int* __restrict__ col, const float* __restrict__ ew,
                      float* __restrict__ deg, int* __restrict__ cnt){
  int e = blockIdx.x * 256 + threadIdx.x;
  if (e < NEDGE){
    int c = col[e];
    atomicAdd(&deg[c], ew[e]);
    atomicAdd(&cnt[c], 1);
  }
}

__global__ void k_dinv(const float* __restrict__ deg, float* __restrict__ dinv, float* __restrict__ srow){
  int i = blockIdx.x * 256 + threadIdx.x;
  if (i < N_NODES){
    float d = deg[i];
    float v = d > 0.f ? rsqrtf(fmaxf(d, EPS)) : 0.f;
    dinv[i] = v; srow[i] = v * v;       // srow starts with self-loop norm
  }
}

__global__ __launch_bounds__(256) void k_chunksum(const int* __restrict__ cnt, int* __restrict__ csum){
  int b = blockIdx.x, t = threadIdx.x;
  int s = 0;
  for (int i = t; i < 1024; i += 256){ int idx = b * 1024 + i; if (idx < N_NODES) s += cnt[idx]; }
  __shared__ int red[256];
  red[t] = s; __syncthreads();
  for (int o = 128; o > 0; o >>= 1){ if (t < o) red[t] += red[t + o]; __syncthreads(); }
  if (t == 0) csum[b] = red[0];
}

__global__ __launch_bounds__(128) void k_chunkscan(const int* __restrict__ csum, int* __restrict__ coff,
                                                   int* __restrict__ ptrA){
  int t = threadIdx.x;
  __shared__ int s[128];
  int v = (t < 98) ? csum[t] : 0;
  s[t] = v; __syncthreads();
  for (int o = 1; o < 128; o <<= 1){
    int x = (t >= o) ? s[t - o] : 0;
    __syncthreads(); s[t] += x; __syncthreads();
  }
  if (t < 98) coff[t] = s[t] - v;       // exclusive chunk offsets
  if (t == 0) ptrA[N_NODES] = NEDGE;
}

__global__ __launch_bounds__(256) void k_scan2(const int* __restrict__ cnt, const int* __restrict__ coff,
                                               int* __restrict__ ptrA){
  int b = blockIdx.x, t = threadIdx.x;
  int base = b * 1024 + t * 4;
  int v[4], tot = 0;
  #pragma unroll
  for (int k = 0; k < 4; k++){ int idx = base + k; v[k] = (idx < N_NODES) ? cnt[idx] : 0; tot += v[k]; }
  __shared__ int sc[256];
  sc[t] = tot; __syncthreads();
  for (int o = 1; o < 256; o <<= 1){
    int x = (t >= o) ? sc[t - o] : 0;
    __syncthreads(); sc[t] += x; __syncthreads();
  }
  int off = coff[b] + sc[t] - tot;
  #pragma unroll
  for (int k = 0; k < 4; k++){ int idx = base + k; if (idx < N_NODES) ptrA[idx] = off; off += v[k]; }
}

// fill CSR + accumulate srow (merged, one edge pass)
__global__ void k_fill(const int* __restrict__ row, const int* __restrict__ col,
                       const float* __restrict__ ew, const float* __restrict__ dinv,
                       const int* __restrict__ ptrA, int* __restrict__ fill, int2* __restrict__ adj,
                       float* __restrict__ srow){
  int e = blockIdx.x * 256 + threadIdx.x;
  if (e < NEDGE){
    int r = row[e], c = col[e];
    float w = dinv[r] * ew[e] * dinv[c];
    int pos = ptrA[c] + atomicAdd(&fill[c], 1);
    adj[pos] = make_int2(r, __float_as_int(w));
    atomicAdd(&srow[c], w);
  }
}

// ---------------- degree counting sort: perm = rows sorted by in-degree (descending) ----------------
// wave uniformity: each wave's 16 rows then have ~equal degree -> wmax ~ avg, no dummy slots.
__global__ __launch_bounds__(256) void k_dhist(const int* __restrict__ cnt, int* __restrict__ dpart){
  __shared__ int loc[256];
  int t = threadIdx.x, blk = blockIdx.x;
  loc[t] = 0;
  __syncthreads();
  int i = blk * 256 + t;
  if (i < N_NODES) atomicAdd(&loc[min(cnt[i], 255)], 1);
  __syncthreads();
  dpart[blk * 256 + t] = loc[t];
}

__global__ __launch_bounds__(256) void k_dscan(int* __restrict__ dpart){
  __shared__ int tot[256], sfx[256];
  int t = threadIdx.x;
  int s = 0;
  for (int p = 0; p < 391; p++) s += dpart[p * 256 + t];
  tot[t] = s;
  sfx[t] = s;
  __syncthreads();
  for (int o = 1; o < 256; o <<= 1){
    int x = (t + o < 256) ? sfx[t + o] : 0;
    __syncthreads(); sfx[t] += x; __syncthreads();
  }
  int run = sfx[t] - tot[t];            // descending: bins > t come first
  for (int p = 0; p < 391; p++){
    int tmp = dpart[p * 256 + t];
    dpart[p * 256 + t] = run;
    run += tmp;
  }
}

__global__ __launch_bounds__(256) void k_dscatter(const int* __restrict__ cnt, const int* __restrict__ dpart,
                                                  int* __restrict__ perm){
  __shared__ int loc[256];
  int t = threadIdx.x, blk = blockIdx.x;
  loc[t] = dpart[blk * 256 + t];
  __syncthreads();
  int i = blk * 256 + t;
  if (i < N_NODES){
    int b = min(cnt[i], 255);
    int pos = atomicAdd(&loc[b], 1);
    perm[pos] = i;
  }
}

// per-block LDS histogram -> partials (no global atomics)
__global__ __launch_bounds__(256) void k_bhist(const int* __restrict__ batch, int* __restrict__ bpart){
  __shared__ int loc[128];
  int t = threadIdx.x;
  if (t < 128) loc[t] = 0;
  __syncthreads();
  int i = blockIdx.x * 256 + t;
  if (i < N_NODES) atomicAdd(&loc[batch[i]], 1);
  __syncthreads();
  if (t < 128) bpart[blockIdx.x * 128 + t] = loc[t];
}

__global__ __launch_bounds__(128) void k_bscan(const int* __restrict__ bpart, int* __restrict__ gptr){
  int t = threadIdx.x;
  int v = 0;
  for (int p = 0; p < 391; p++) v += bpart[p * 128 + t];
  __shared__ int s[128];
  s[t] = v; __syncthreads();
  for (int o = 1; o < 128; o <<= 1){
    int x = (t >= o) ? s[t - o] : 0;
    __syncthreads(); s[t] += x; __syncthreads();
  }
  gptr[t + 1] = s[t];
  if (t == 0) gptr[0] = 0;
}

// ---------------- x (f32) -> bf16 staging + column stats (fused, one pass) ----------------
__global__ __launch_bounds__(256) void k_cvtstats(const float* __restrict__ x, u32* __restrict__ dst,
                                                  float* __restrict__ sums_out){
  __shared__ float R[1024];
  int t = threadIdx.x;
  float s0 = 0.f, q0 = 0.f, s1 = 0.f, q1 = 0.f;
  size_t base = (size_t)blockIdx.x * 4096 + t;
  #pragma unroll
  for (int it = 0; it < 16; it++){
    size_t idx = base + (size_t)it * 256;
    if (idx < (size_t)N_NODES * 64){
      float2 v = ((const float2*)x)[idx];
      dst[idx] = (u32)f2bf(v.x) | ((u32)f2bf(v.y) << 16);
      s0 += v.x; q0 += v.x * v.x; s1 += v.y; q1 += v.y * v.y;
    }
  }
  R[t] = s0; R[256 + t] = q0; R[512 + t] = s1; R[768 + t] = q1;
  __syncthreads();
  if (t < 64){
    float S0 = 0.f, Q0 = 0.f, S1 = 0.f, Q1 = 0.f;
    #pragma unroll
    for (int g = 0; g < 4; g++){
      S0 += R[g * 64 + t];       Q0 += R[256 + g * 64 + t];
      S1 += R[512 + g * 64 + t]; Q1 += R[768 + g * 64 + t];
    }
    float* so = sums_out + (blockIdx.x & (NSLOT - 1)) * 256;
    atomicAdd(&so[2 * t], S0);
    atomicAdd(&so[2 * t + 1], S1);
    atomicAdd(&so[128 + 2 * t], Q0);
    atomicAdd(&so[128 + 2 * t + 1], Q1);
  }
}

// ---------------- per-layer fold: BN into fragment-ordered hi/lo bf16 W + rank-one ----------------
__device__ __forceinline__ void fold_body(int blk, int t, const float* __restrict__ sums,
    const float* __restrict__ bw, const float* __restrict__ bb,
    const float* __restrict__ W, const float* __restrict__ bias,
    u16* __restrict__ Wh, u16* __restrict__ Wl, float* __restrict__ rb,
    float* scl, float* shf, float* stot, float* rred){
  {
    float s = 0.f;
    #pragma unroll 4
    for (int sl = 0; sl < NSLOT; sl++) s += sums[sl * 256 + t];
    stot[t] = s;
  }
  __syncthreads();
  if (t < 128){
    float mu  = stot[t] * (1.f / N_NODES);
    float var = stot[128 + t] * (1.f / N_NODES) - mu * mu;
    float sc  = bw[t] * rsqrtf(var + EPS);
    scl[t] = sc; shf[t] = bb[t] - mu * sc;
  }
  __syncthreads();
  {
    int idx = blk * 256 + t;
    int lane_ = idx & 63, sl = idx >> 6;   // sl = nt*4 + ks
    int nt_ = sl >> 2, ks_ = sl & 3;
    int n_ = nt_ * 16 + (lane_ & 15);
    int kb = ks_ * 32 + (lane_ >> 4) * 8;
    u16 hi8[8], lo8[8];
    #pragma unroll
    for (int j = 0; j < 8; j++){
      float wv = W[(kb + j) * 128 + n_];
      float xv = scl[kb + j] * wv;
      u16 hh = f2bf(xv);
      hi8[j] = hh; lo8[j] = f2bf(xv - bf2f(hh));
    }
    uint4 ph, pl;
    ph.x = (u32)hi8[0] | ((u32)hi8[1] << 16); ph.y = (u32)hi8[2] | ((u32)hi8[3] << 16);
    ph.z = (u32)hi8[4] | ((u32)hi8[5] << 16); ph.w = (u32)hi8[6] | ((u32)hi8[7] << 16);
    pl.x = (u32)lo8[0] | ((u32)lo8[1] << 16); pl.y = (u32)lo8[2] | ((u32)lo8[3] << 16);
    pl.z = (u32)lo8[4] | ((u32)lo8[5] << 16); pl.w = (u32)lo8[6] | ((u32)lo8[7] << 16);
    *(uint4*)&Wh[idx * 8] = ph;
    *(uint4*)&Wl[idx * 8] = pl;
  }
  {
    int nl = t & 15, kk = t >> 4;
    int n2 = blk * 16 + nl;
    float rp = 0.f;
    #pragma unroll
    for (int j = 0; j < 8; j++){
      int k2 = kk * 8 + j;
      rp += shf[k2] * W[k2 * 128 + n2];
    }
    rred[t] = rp;
  }
  __syncthreads();
  if (t < 16){
    float s = 0.f;
    #pragma unroll
    for (int kk2 = 0; kk2 < 16; kk2++) s += rred[kk2 * 16 + t];
    int n2 = blk * 16 + t;
    rb[n2] = s;
    rb[128 + n2] = bias[n2];
  }
}

__global__ __launch_bounds__(256) void k_fold(const float* __restrict__ sums,
    const float* __restrict__ bw, const float* __restrict__ bb,
    const float* __restrict__ W, const float* __restrict__ bias,
    u16* __restrict__ Wh, u16* __restrict__ Wl, float* __restrict__ rb){
  __shared__ float scl[128], shf[128], stot[256], rred[256];
  fold_body(blockIdx.x, threadIdx.x, sums, bw, bb, W, bias, Wh, Wl, rb, scl, shf, stot, rred);
}

__global__ __launch_bounds__(256) void k_fold2(
    const float* __restrict__ sumsA, const float* __restrict__ bwA, const float* __restrict__ bbA,
    const float* __restrict__ WA, const float* __restrict__ biasA,
    u16* __restrict__ WhA, u16* __restrict__ WlA, float* __restrict__ rbA,
    const float* __restrict__ sumsB, const float* __restrict__ bwB, const float* __restrict__ bbB,
    const float* __restrict__ WB, const float* __restrict__ biasB,
    u16* __restrict__ WhB, u16* __restrict__ WlB, float* __restrict__ rbB){
  __shared__ float scl[128], shf[128], stot[256], rred[256];
  int bb_ = blockIdx.x;
  if (bb_ < 8)
    fold_body(bb_, threadIdx.x, sumsA, bwA, bbA, WA, biasA, WhA, WlA, rbA, scl, shf, stot, rred);
  else
    fold_body(bb_ - 8, threadIdx.x, sumsB, bwB, bbB, WB, biasB, WhB, WlB, rbB, scl, shf, stot, rred);
}

// ---------------- epilogue macro: bias + rank-one + relu + store (via perm) + slotted stats ----------------
#define CONV_EPILOGUE(RB, HOUT, SOUT, BLK)                                     \
  __syncthreads();                                                             \
  sred[t] = 0.f;                                                               \
  __syncthreads();                                                             \
  _Pragma("unroll")                                                            \
  for (int nt = 0; nt < 8; nt++){                                              \
    int colc = nt * 16 + m;                                                    \
    float rv = RB[colc], bv = RB[128 + colc];                                  \
    float s = 0.f, qq = 0.f;                                                   \
    _Pragma("unroll")                                                          \
    for (int r = 0; r < 4; r++){                                               \
      int pr = prow[r];                                                        \
      if (pr >= 0){                                                            \
        float v = C[nt][r] + srow[pr] * rv + bv;                               \
        v = fmaxf(v, 0.f);                                                     \
        u16 sv = f2bf(v);                                                      \
        HOUT[(size_t)pr * 128 + colc] = sv;                                    \
        float vv = bf2f(sv); s += vv; qq += vv * vv;                           \
      }                                                                        \
    }                                                                          \
    s  += __shfl_xor(s, 16, 64);  s  += __shfl_xor(s, 32, 64);                 \
    qq += __shfl_xor(qq, 16, 64); qq += __shfl_xor(qq, 32, 64);                \
    if (q == 0){                                                               \
      atomicAdd(&sred[colc], s);                                               \
      atomicAdd(&sred[128 + colc], qq);                                        \
    }                                                                          \
  }                                                                            \
  __syncthreads();                                                             \
  atomicAdd(&SOUT[((BLK) & (NSLOT - 1)) * 256 + t], sred[t]);

#define FMA_KS(KS, V, WT) \
  acc[KS][0] += (WT) * __uint_as_float((V).x << 16); acc[KS][1] += (WT) * __uint_as_float((V).x & 0xffff0000u); \
  acc[KS][2] += (WT) * __uint_as_float((V).y << 16); acc[KS][3] += (WT) * __uint_as_float((V).y & 0xffff0000u); \
  acc[KS][4] += (WT) * __uint_as_float((V).z << 16); acc[KS][5] += (WT) * __uint_as_float((V).z & 0xffff0000u); \
  acc[KS][6] += (WT) * __uint_as_float((V).w << 16); acc[KS][7] += (WT) * __uint_as_float((V).w & 0xffff0000u);

#define VMCNT6() asm volatile("s_waitcnt vmcnt(6)" ::: "memory")
#define VMCNT5() asm volatile("s_waitcnt vmcnt(5)" ::: "memory")
#define SB0()    __builtin_amdgcn_sched_barrier(0)

// ---------------- LDS-staged gather: global_load_lds double-buffer, counted vmcnt ----------------
// rows assigned via degree-sorted perm -> wave's 16 rows have ~equal degree (wmax ~ deg).
__device__ __forceinline__ void gll_stage(const u16* __restrict__ h, u16* dst, int2 aj, int lane){
  int c = lane & 15, g = lane >> 4;
  #pragma unroll
  for (int ii = 0; ii < 4; ii++){
    int rl = ii * 4 + g;
    int srcrow = __shfl(aj.x, rl, 64);
    const u16* src = h + (size_t)srcrow * 128 + (size_t)((c ^ rl) * 8);
    __builtin_amdgcn_global_load_lds((const void*)src, (void*)(dst + ii * 512), 16, 0, 0);
  }
}

#define GITER(WA, WB, WC, WD, STG, J)                                          \
  WD = *(const int2*)(adj + base_ + min((J) + 3, dcl));                        \
  VMCNT6();                                                                    \
  {                                                                            \
    float wgt = __int_as_float(__shfl((WA).y, m, 64));                         \
    if ((J) < deg){                                                            \
      const u16* sp = stage + (STG) * 2048;                                    \
      _Pragma("unroll")                                                        \
      for (int ks = 0; ks < 4; ks++){                                          \
        int slot = (q + 4 * ks) ^ m;                                           \
        uint4 v = *(const uint4*)(sp + m * 128 + slot * 8);                    \
        FMA_KS(ks, v, wgt)                                                     \
      }                                                                        \
    }                                                                          \
  }                                                                            \
  VMCNT5();                                                                    \
  gll_stage(h, stage + (STG) * 2048, WC, lane);                                \
  SB0();

__device__ __forceinline__ void gather_row_lds(const u16* __restrict__ h,
    const int* __restrict__ ptrA, const int2* __restrict__ adj,
    const float* __restrict__ dinv, const int* __restrict__ perm,
    int row0, int lane, u16* stage, float (&acc)[4][8]){
  int m = lane & 15, q = lane >> 4;
  #pragma unroll
  for (int ks = 0; ks < 4; ks++)
    #pragma unroll
    for (int j = 0; j < 8; j++) acc[ks][j] = 0.f;
  int rl = row0 + m;                                  // logical (sorted) row
  int rp = perm[min(rl, N_NODES - 1)];                // physical node
  int active = rl < N_NODES;
  int b0 = ptrA[rp], b1 = ptrA[rp + 1];
  int deg = active ? (b1 - b0) : 0;
  int base_ = (deg > 0) ? b0 : 0;
  int dcl = max(deg - 1, 0);
  float di = dinv[rp];
  float sw = active ? di * di : 0.f;
  // self-loop (registers; unconditional clamped loads)
  const u16* hq = h + q * 8;
  const u16* sp_ = hq + (size_t)rp * 128;
  uint4 s0 = *(const uint4*)(sp_);
  uint4 s1 = *(const uint4*)(sp_ + 32);
  uint4 s2 = *(const uint4*)(sp_ + 64);
  uint4 s3 = *(const uint4*)(sp_ + 96);
  int2 W0 = *(const int2*)(adj + base_);
  int2 W1 = *(const int2*)(adj + base_ + min(1, dcl));
  // wave-max degree (uniform over wave; ~deg after sorting)
  int wmax = deg;
  wmax = max(wmax, __shfl_xor(wmax, 1, 64));
  wmax = max(wmax, __shfl_xor(wmax, 2, 64));
  wmax = max(wmax, __shfl_xor(wmax, 4, 64));
  wmax = max(wmax, __shfl_xor(wmax, 8, 64));
  FMA_KS(0, s0, sw) FMA_KS(1, s1, sw) FMA_KS(2, s2, sw) FMA_KS(3, s3, sw)
  if (wmax > 0){
    int2 W2 = W0, W3 = W0;
    SB0();
    gll_stage(h, stage, W0, lane);          // edge 0 -> stage 0
    SB0();
    W2 = *(const int2*)(adj + base_ + min(2, dcl));
    SB0();
    gll_stage(h, stage + 2048, W1, lane);   // edge 1 -> stage 1
    SB0();
    int j0 = 0;
    for (;;){
      GITER(W0, W1, W2, W3, 0, j0)
      GITER(W1, W2, W3, W0, 1, j0 + 1)
      j0 += 2; if (j0 >= wmax) break;
      GITER(W2, W3, W0, W1, 0, j0)
      GITER(W3, W0, W1, W2, 1, j0 + 1)
      j0 += 2; if (j0 >= wmax) break;
    }
  }
}

#define BUILD_AFRAG()                                                          \
  bf16x8 AH[4], AL[4];                                                         \
  _Pragma("unroll")                                                            \
  for (int ks = 0; ks < 4; ks++)                                               \
    _Pragma("unroll")                                                          \
    for (int j = 0; j < 8; j++){                                               \
      u16 hh = f2bf(acc[ks][j]);                                               \
      AH[ks][j] = (short)hh;                                                   \
      AL[ks][j] = (short)f2bf(acc[ks][j] - bf2f(hh));                          \
    }

#define PROW_SETUP()                                                           \
  int prow[4];                                                                 \
  _Pragma("unroll")                                                            \
  for (int r_ = 0; r_ < 4; r_++){                                              \
    int rr = row0 + q * 4 + r_;                                                \
    prow[r_] = (rr < N_NODES) ? perm[rr] : -1;                                 \
  }

#define MFMA_3PASS(WH, WL_)                                                    \
  _Pragma("unroll")                                                            \
  for (int ks = 0; ks < 4; ks++){                                              \
    _Pragma("unroll")                                                          \
    for (int nt = 0; nt < 8; nt++){                                            \
      bf16x8 bh = ((const bf16x8*)WH)[(nt * 4 + ks) * 64 + lane];              \
      bf16x8 bl = ((const bf16x8*)WL_)[(nt * 4 + ks) * 64 + lane];             \
      C[nt] = __builtin_amdgcn_mfma_f32_16x16x32_bf16(AH[ks], bh, C[nt], 0, 0, 0); \
      C[nt] = __builtin_amdgcn_mfma_f32_16x16x32_bf16(AL[ks], bh, C[nt], 0, 0, 0); \
      C[nt] = __builtin_amdgcn_mfma_f32_16x16x32_bf16(AH[ks], bl, C[nt], 0, 0, 0); \
    }                                                                          \
  }

// ---------------- fused conv: LDS-staged gather + MFMA (b-frags from global) + stats ----------------
__global__ __launch_bounds__(256, 3) void k_conv(
    const u16* __restrict__ h, const int* __restrict__ ptrA, const int2* __restrict__ adj,
    const float* __restrict__ dinv, const float* __restrict__ srow, const int* __restrict__ perm,
    const u16* __restrict__ Wh, const u16* __restrict__ Wl, const float* __restrict__ rb,
    u16* __restrict__ hout, float* __restrict__ sums_out){
  __shared__ u16 hstage[4][2][2048];
  __shared__ float sred[256];
  int t = threadIdx.x;
  int wave = t >> 6, lane = t & 63, m = lane & 15, q = lane >> 4;
  int blk = blockIdx.x;
  int row0 = blk * 64 + wave * 16;
  float acc[4][8];
  gather_row_lds(h, ptrA, adj, dinv, perm, row0, lane, &hstage[wave][0][0], acc);
  BUILD_AFRAG()
  PROW_SETUP()
  f32x4 C[8];
  #pragma unroll
  for (int nt = 0; nt < 8; nt++) C[nt] = f32x4{0.f, 0.f, 0.f, 0.f};
  MFMA_3PASS(Wh, Wl)
  CONV_EPILOGUE(rb, hout, sums_out, blk)
}

// ---------------- paired conv: two independent convs in one launch (grid 2*NBLK) ----------------
__global__ __launch_bounds__(256, 3) void k_conv2(
    const u16* __restrict__ hA, const u16* __restrict__ hB,
    const int* __restrict__ ptrA, const int2* __restrict__ adj,
    const float* __restrict__ dinv, const float* __restrict__ srow, const int* __restrict__ perm,
    const u16* __restrict__ WhA, const u16* __restrict__ WlA, const float* __restrict__ rbA,
    u16* __restrict__ houtA, float* __restrict__ sumsA,
    const u16* __restrict__ WhB, const u16* __restrict__ WlB, const float* __restrict__ rbB,
    u16* __restrict__ houtB, float* __restrict__ sumsB){
  __shared__ u16 hstage[4][2][2048];
  __shared__ float sred[256];
  int t = threadIdx.x;
  int wave = t >> 6, lane = t & 63, m = lane & 15, q = lane >> 4;
  int bb = blockIdx.x;
  int second = bb >= NBLK;
  int blk = second ? bb - NBLK : bb;
  const u16* h = second ? hB : hA;
  const u16* Wh = second ? WhB : WhA;
  const u16* Wl = second ? WlB : WlA;
  const float* rb = second ? rbB : rbA;
  u16* hout = second ? houtB : houtA;
  float* sums_out = second ? sumsB : sumsA;
  int row0 = blk * 64 + wave * 16;
  float acc[4][8];
  gather_row_lds(h, ptrA, adj, dinv, perm, row0, lane, &hstage[wave][0][0], acc);
  BUILD_AFRAG()
  PROW_SETUP()
  f32x4 C[8];
  #pragma unroll
  for (int nt = 0; nt < 8; nt++) C[nt] = f32x4{0.f, 0.f, 0.f, 0.f};
  MFMA_3PASS(Wh, Wl)
  CONV_EPILOGUE(rb, hout, sums_out, blk)
}

// ---------------- dual conv: one gather, two folded-W phases (a2 & c2 share S@a1) ----------------
__global__ __launch_bounds__(256, 3) void k_dualconv(
    const u16* __restrict__ h, const int* __restrict__ ptrA, const int2* __restrict__ adj,
    const float* __restrict__ dinv, const float* __restrict__ srow, const int* __restrict__ perm,
    const u16* __restrict__ Wh1, const u16* __restrict__ Wl1, const float* __restrict__ rb1,
    u16* __restrict__ hout1, float* __restrict__ sums1,
    const u16* __restrict__ Wh2, const u16* __restrict__ Wl2, const float* __restrict__ rb2,
    u16* __restrict__ hout2, float* __restrict__ sums2){
  __shared__ u16 hstage[4][2][2048];
  __shared__ float sred[256];
  int t = threadIdx.x;
  int wave = t >> 6, lane = t & 63, m = lane & 15, q = lane >> 4;
  int blk = blockIdx.x;
  int row0 = blk * 64 + wave * 16;
  float acc[4][8];
  gather_row_lds(h, ptrA, adj, dinv, perm, row0, lane, &hstage[wave][0][0], acc);
  BUILD_AFRAG()
  PROW_SETUP()
  f32x4 C[8];
  #pragma unroll
  for (int nt = 0; nt < 8; nt++) C[nt] = f32x4{0.f, 0.f, 0.f, 0.f};
  MFMA_3PASS(Wh1, Wl1)
  CONV_EPILOGUE(rb1, hout1, sums1, blk)
  #pragma unroll
  for (int nt = 0; nt < 8; nt++) C[nt] = f32x4{0.f, 0.f, 0.f, 0.f};
  MFMA_3PASS(Wh2, Wl2)
  CONV_EPILOGUE(rb2, hout2, sums2, blk)
}

// ---------------- branch-4 elementwise: out = relu(bn(h)); slotted stats ----------------
__global__ __launch_bounds__(256) void k_normrelu(const u16* __restrict__ h, const float* __restrict__ sums,
    const float* __restrict__ bw, const float* __restrict__ bb, u16* __restrict__ o,
    float* __restrict__ sums_out){
  __shared__ float scl[128], shf[128], R[1024], stot[256];
  int t = threadIdx.x;
  {
    float s = 0.f;
    #pragma unroll 4
    for (int sl = 0; sl < NSLOT; sl++) s += sums[sl * 256 + t];
    stot[t] = s;
  }
  __syncthreads();
  if (t < 128){
    float mu  = stot[t] * (1.f / N_NODES);
    float var = stot[128 + t] * (1.f / N_NODES) - mu * mu;
    float sc  = bw[t] * rsqrtf(var + EPS);
    scl[t] = sc; shf[t] = bb[t] - mu * sc;
  }
  __syncthreads();
  int c0 = (t & 63) * 2;
  float sc0 = scl[c0], sh0 = shf[c0], sc1 = scl[c0 + 1], sh1 = shf[c0 + 1];
  float s0 = 0.f, q0 = 0.f, s1 = 0.f, q1 = 0.f;
  size_t base = (size_t)blockIdx.x * 4096 + t;
  #pragma unroll
  for (int it = 0; it < 16; it++){
    size_t idx = base + (size_t)it * 256;
    if (idx < (size_t)N_NODES * 64){
      u32 v = ((const u32*)h)[idx];
      float x0 = fmaxf(bf2f(v & 0xffffu) * sc0 + sh0, 0.f);
      float x1 = fmaxf(bf2f(v >> 16) * sc1 + sh1, 0.f);
      u16 r0 = f2bf(x0), r1 = f2bf(x1);
      ((u32*)o)[idx] = (u32)r0 | ((u32)r1 << 16);
      float y0 = bf2f(r0), y1 = bf2f(r1);
      s0 += y0; q0 += y0 * y0; s1 += y1; q1 += y1 * y1;
    }
  }
  R[t] = s0; R[256 + t] = q0; R[512 + t] = s1; R[768 + t] = q1;
  __syncthreads();
  if (t < 64){
    float S0 = 0.f, Q0 = 0.f, S1 = 0.f, Q1 = 0.f;
    #pragma unroll
    for (int g = 0; g < 4; g++){
      S0 += R[g * 64 + t];       Q0 += R[256 + g * 64 + t];
      S1 += R[512 + g * 64 + t]; Q1 += R[768 + g * 64 + t];
    }
    float* so = sums_out + (blockIdx.x & (NSLOT - 1)) * 256;
    atomicAdd(&so[2 * t], S0);
    atomicAdd(&so[2 * t + 1], S1);
    atomicAdd(&so[128 + 2 * t], Q0);
    atomicAdd(&so[128 + 2 * t + 1], Q1);
  }
}

// ---------------- global_add_pool ----------------
__global__ __launch_bounds__(128) void k_pool(const u16* __restrict__ h, const int* __restrict__ gptr,
                                              float* __restrict__ gdst){
  int g = blockIdx.x >> 3, s = blockIdx.x & 7, t = threadIdx.x;
  int b = gptr[g], e = gptr[g + 1];
  int len = e - b, per = (len + 7) >> 3;
  int r0 = b + s * per, r1 = min(r0 + per, e);
  float acc = 0.f;
  for (int r = r0; r < r1; r++) acc += bf2f(h[(size_t)r * 128 + t]);
  atomicAdd(&gdst[g * 128 + t], acc);
}

// ---------------- head: 8x8 register-tile FC, shfl-reduced classifier ----------------
__global__ __launch_bounds__(256) void k_head(const float* __restrict__ gbuf,
    const float* __restrict__ fcw, const float* __restrict__ fcb,
    const float* __restrict__ Wfc, const float* __restrict__ bfc,
    const float* __restrict__ bhw, const float* __restrict__ bhb,
    const float* __restrict__ Wcl, const float* __restrict__ bcl,
    float* __restrict__ out){
  __shared__ float GS[128 * 65];           // Gbn k-half staging (33 KB)
  __shared__ float ls[256], lq[256];
  __shared__ float scl[128], shf[128], scl2[128], shf2[128];
  __shared__ float sumT[128], sumQ[128];
  __shared__ float WclT[1280], Lrow[1280];
  int t = threadIdx.x, br = blockIdx.x;
  int slot = (br == 1) ? 1 : (br == 3 ? 3 : 0);   // branch3 == branch1 (slot 0)
  const float* G = gbuf + slot * 16384;
  { // stats of G
    int col = t & 127, hf2 = t >> 7;
    float s = 0.f, q = 0.f;
    for (int g = hf2 * 64; g < hf2 * 64 + 64; g++){ float v = G[g * 128 + col]; s += v; q += v * v; }
    ls[t] = s; lq[t] = q;
  }
  for (int idx = t; idx < 1280; idx += 256){     // WclT[cc][c] = Wcl[c][cc]
    int cc = idx >> 7, c = idx & 127;
    WclT[idx] = Wcl[c * 10 + cc];
  }
  if (t < 128){ sumT[t] = 0.f; sumQ[t] = 0.f; }
  __syncthreads();
  if (t < 128){
    float s = ls[t] + ls[t + 128], q = lq[t] + lq[t + 128];
    float mu = s * (1.f / 128), var = q * (1.f / 128) - mu * mu;
    float sc = fcw[t] * rsqrtf(var + EPS);
    scl[t] = sc; shf[t] = fcb[t] - mu * sc;
  }
  __syncthreads();
  int tr = t >> 4, tc = t & 15, r0 = tr * 8, c0 = tc * 8;
  float acc[8][8];
  #pragma unroll
  for (int a = 0; a < 8; a++)
    #pragma unroll
    for (int b = 0; b < 8; b++) acc[a][b] = 0.f;
  for (int kh = 0; kh < 2; kh++){
    for (int idx = t; idx < 8192; idx += 256){
      int r = idx >> 6, kk = idx & 63, f = kh * 64 + kk;
      GS[r * 65 + kk] = G[r * 128 + f] * scl[f] + shf[f];
    }
    __syncthreads();
    #pragma unroll 2
    for (int k = 0; k < 64; k++){
      float a[8];
      #pragma unroll
      for (int ri = 0; ri < 8; ri++) a[ri] = GS[(r0 + ri) * 65 + k];
      float4 b0 = *(const float4*)&Wfc[(kh * 64 + k) * 128 + c0];
      float4 b1 = *(const float4*)&Wfc[(kh * 64 + k) * 128 + c0 + 4];
      float bb[8] = {b0.x, b0.y, b0.z, b0.w, b1.x, b1.y, b1.z, b1.w};
      #pragma unroll
      for (int ri = 0; ri < 8; ri++)
        #pragma unroll
        for (int ci = 0; ci < 8; ci++) acc[ri][ci] += a[ri] * bb[ci];
    }
    __syncthreads();
  }
  #pragma unroll
  for (int ci = 0; ci < 8; ci++){
    float bb = bfc[c0 + ci];
    float s = 0.f, q = 0.f;
    #pragma unroll
    for (int ri = 0; ri < 8; ri++){
      float v = fmaxf(acc[ri][ci] + bb, 0.f);
      acc[ri][ci] = v; s += v; q += v * v;
    }
    atomicAdd(&sumT[c0 + ci], s);
    atomicAdd(&sumQ[c0 + ci], q);
  }
  __syncthreads();
  if (t < 128){
    float mu = sumT[t] * (1.f / 128), var = sumQ[t] * (1.f / 128) - mu * mu;
    float sc = bhw[t] * rsqrtf(var + EPS);
    scl2[t] = sc; shf2[t] = bhb[t] - mu * sc;
  }
  __syncthreads();
  #pragma unroll
  for (int ci = 0; ci < 8; ci++){
    float sc = scl2[c0 + ci], sh = shf2[c0 + ci];
    #pragma unroll
    for (int ri = 0; ri < 8; ri++) acc[ri][ci] = acc[ri][ci] * sc + sh;
  }
  #pragma unroll
  for (int ri = 0; ri < 8; ri++){
    float pl[10];
    #pragma unroll
    for (int cc = 0; cc < 10; cc++) pl[cc] = 0.f;
    #pragma unroll
    for (int ci = 0; ci < 8; ci++){
      float v = acc[ri][ci];
      #pragma unroll
      for (int cc = 0; cc < 10; cc++) pl[cc] += v * WclT[cc * 128 + c0 + ci];
    }
    #pragma unroll
    for (int msk = 1; msk < 16; msk <<= 1)
      #pragma unroll
      for (int cc = 0; cc < 10; cc++) pl[cc] += __shfl_xor(pl[cc], msk, 64);
    if (tc == 0)
      #pragma unroll
      for (int cc = 0; cc < 10; cc++) Lrow[(r0 + ri) * 10 + cc] = pl[cc];
  }
  __syncthreads();
  if (t < 128){
    float l[10];
    #pragma unroll
    for (int cc = 0; cc < 10; cc++) l[cc] = Lrow[t * 10 + cc] + bcl[cc];
    float m = l[0];
    #pragma unroll
    for (int cc = 1; cc < 10; cc++) m = fmaxf(m, l[cc]);
    float se = 0.f;
    #pragma unroll
    for (int cc = 0; cc < 10; cc++) se += expf(l[cc] - m);
    float lse = m + logf(se);
    #pragma unroll
    for (int cc = 0; cc < 10; cc++) out[br * 1280 + t * 10 + cc] = l[cc] - lse;
  }
}

extern "C" void kernel_launch(void* const* d_in, const int* in_sizes, int n_in,
                              void* d_out, int out_size, void* d_ws, size_t ws_size,
                              hipStream_t stream){
  const float* x    = (const float*)d_in[0];
  const int*  ei    = (const int*)d_in[1];      // [2,E]: rows then cols
  const int*  batch = (const int*)d_in[2];
  const float* ew   = (const float*)d_in[3];
  const float* bnfw = (const float*)d_in[4];
  const float* bnfb = (const float*)d_in[5];
  const float* cfW  = (const float*)d_in[6];
  const float* cfb  = (const float*)d_in[7];
  const float* bnsw = (const float*)d_in[8];
  const float* bnsb = (const float*)d_in[9];
  const float* cvW  = (const float*)d_in[10];
  const float* cvb  = (const float*)d_in[11];
  const float* fcw  = (const float*)d_in[12];
  const float* fcb  = (const float*)d_in[13];
  const float* Wfc  = (const float*)d_in[14];
  const float* bfc  = (const float*)d_in[15];
  const float* bhw  = (const float*)d_in[16];
  const float* bhb  = (const float*)d_in[17];
  const float* Wcl  = (const float*)d_in[18];
  const float* bcl  = (const float*)d_in[19];
  float* out = (float*)d_out;

  char* p = (char*)d_ws;
  auto carve = [&](size_t bytes)->void*{ void* r = (void*)p; p += (bytes + 255) & ~(size_t)255; return r; };
  float* deg  = (float*)carve((size_t)NPAD * 4);
  float* dinv = (float*)carve((size_t)NPAD * 4);
  float* srow = (float*)carve((size_t)NPAD * 4);
  int*   cnt  = (int*)carve((size_t)NPAD * 4);
  int*   fill = (int*)carve((size_t)NPAD * 4);
  int*   ptrA = (int*)carve((size_t)(NPAD + 1) * 4);
  int*   perm = (int*)carve((size_t)NPAD * 4);
  int*   bpart= (int*)carve((size_t)391 * 128 * 4);
  int*   dpart= (int*)carve((size_t)391 * 256 * 4);
  int*   csum = (int*)carve(512);
  int*   coff = (int*)carve(512);
  int*   gptr = (int*)carve(1024);
  float* S    = (float*)carve((size_t)13 * NSLOT * 1024);   // 13 steps x NSLOT x 256 floats
  float* gbuf = (float*)carve(4 * 128 * 128 * 4);
  u16*   F0h  = (u16*)carve(32768);  u16* F0l = (u16*)carve(32768);  float* F0r = (float*)carve(1024);
  u16*   F1h  = (u16*)carve(32768);  u16* F1l = (u16*)carve(32768);  float* F1r = (float*)carve(1024);
  u16*   F2h  = (u16*)carve(32768);  u16* F2l = (u16*)carve(32768);  float* F2r = (float*)carve(1024);
  u16*   B0   = (u16*)carve((size_t)NPAD * 256);
  u16*   B1   = (u16*)carve((size_t)NPAD * 256);
  u16*   B2   = (u16*)carve((size_t)NPAD * 256);
  u16*   B3   = (u16*)carve((size_t)NPAD * 256);
  int2*  adj  = (int2*)carve((size_t)NEDGE * 8);
  u16*   Xb   = B3;   // bf16 x staging; B3's first real write (d2) is after L0 conv consumes Xb
  auto Sb = [&](int i){ return S + (size_t)i * NSLOT * 256; };

  (void)hipMemsetAsync(S, 0, (size_t)13 * NSLOT * 1024, stream);

  // preprocessing: degrees, norms, CSR, degree-sort, group offsets
  k_init<<<392, 256, 0, stream>>>(deg, cnt, fill, gbuf);
  k_deg<<<3125, 256, 0, stream>>>(ei + NEDGE, ew, deg, cnt);
  k_dinv<<<391, 256, 0, stream>>>(deg, dinv, srow);
  k_dhist<<<391, 256, 0, stream>>>(cnt, dpart);
  k_dscan<<<1, 256, 0, stream>>>(dpart);
  k_dscatter<<<391, 256, 0, stream>>>(cnt, dpart, perm);
  k_chunksum<<<98, 256, 0, stream>>>(cnt, csum);
  k_chunkscan<<<1, 128, 0, stream>>>(csum, coff, ptrA);
  k_scan2<<<98, 256, 0, stream>>>(cnt, coff, ptrA);
  k_fill<<<3125, 256, 0, stream>>>(ei, ei + NEDGE, ew, dinv, ptrA, fill, adj, srow);
  k_bhist<<<391, 256, 0, stream>>>(batch, bpart);
  k_bscan<<<1, 128, 0, stream>>>(bpart, gptr);
  k_cvtstats<<<NBLK, 256, 0, stream>>>(x, (u32*)Xb, Sb(0));

  auto fold = [&](const float* Sin, const float* bw, const float* bb,
                  const float* W, const float* bias, u16* Fh, u16* Fl, float* Fr){
    k_fold<<<8, 256, 0, stream>>>(Sin, bw, bb, W, bias, Fh, Fl, Fr);
  };
  auto conv = [&](const u16* hin, const u16* Fh, const u16* Fl, const float* Fr,
                  u16* hout, float* Sout){
    k_conv<<<NBLK, 256, 0, stream>>>(hin, ptrA, adj, dinv, srow, perm, Fh, Fl, Fr, hout, Sout);
  };

  // L0: h_init = relu(conv(bn_feat(x)))
  fold(Sb(0), bnfw, bnfb, cfW, cfb, F0h, F0l, F0r);
  conv(Xb, F0h, F0l, F0r, B0, Sb(1));                                         // B0 = h_init
  // a1 = step(h_init, bn0/W0)  (== branch2 c1)
  fold(Sb(1), bnsw, bnsb, cvW, cvb, F1h, F1l, F1r);
  conv(B0, F1h, F1l, F1r, B1, Sb(2));                                         // B1 = a1
  // branch 4: d1,d2,d3 (d1 uses stats(h_init))
  k_normrelu<<<NBLK, 256, 0, stream>>>(B0, Sb(1), bnsw,       bnsb,       B2, Sb(3));   // d1 -> B2
  k_normrelu<<<NBLK, 256, 0, stream>>>(B2, Sb(3), bnsw + 128, bnsb + 128, B3, Sb(4));   // d2 -> B3
  k_normrelu<<<NBLK, 256, 0, stream>>>(B3, Sb(4), bnsw + 256, bnsb + 256, B2, Sb(12));  // d3 -> B2
  k_pool<<<1024, 128, 0, stream>>>(B2, gptr, gbuf + 3 * 16384);
  // dual: a2 = step(a1, bn1/W1), c2 = step(a1, bn0/W0) — one gather of S@a1; both folds one launch
  k_fold2<<<16, 256, 0, stream>>>(
      Sb(2), bnsw + 128, bnsb + 128, cvW + 16384, cvb + 128, F0h, F0l, F0r,
      Sb(2), bnsw,       bnsb,       cvW,         cvb,       F1h, F1l, F1r);
  k_dualconv<<<NBLK, 256, 0, stream>>>(B1, ptrA, adj, dinv, srow, perm,
      F0h, F0l, F0r, B3, Sb(5),       // a2 -> B3
      F1h, F1l, F1r, B2, Sb(6));      // c2 -> B2
  // a3 = step(a2, bn2/W2) -> branches 1 & 3 ; c3 = step(c2, bn1/W1) — independent, one launch
  k_fold2<<<16, 256, 0, stream>>>(
      Sb(5), bnsw + 256, bnsb + 256, cvW + 32768, cvb + 256, F2h, F2l, F2r,
      Sb(6), bnsw + 128, bnsb + 128, cvW + 16384, cvb + 128, F0h, F0l, F0r);
  k_conv2<<<2 * NBLK, 256, 0, stream>>>(B3, B2, ptrA, adj, dinv, srow, perm,
      F2h, F2l, F2r, B0, Sb(10),      // a3 -> B0
      F0h, F0l, F0r, B1, Sb(7));      // c3 -> B1
  k_pool<<<1024, 128, 0, stream>>>(B0, gptr, gbuf);
  // c4 = step(c3, bn1/W1)
  fold(Sb(7), bnsw + 128, bnsb + 128, cvW + 16384, cvb + 128, F1h, F1l, F1r);
  conv(B1, F1h, F1l, F1r, B2, Sb(8));                                         // c4 -> B2
  // c5 = step(c4, bn2/W2)
  fold(Sb(8), bnsw + 256, bnsb + 256, cvW + 32768, cvb + 256, F2h, F2l, F2r);
  conv(B2, F2h, F2l, F2r, B1, Sb(9));                                         // c5 -> B1
  // c6 = step(c5, bn2/W2) -> branch 2
  fold(Sb(9), bnsw + 256, bnsb + 256, cvW + 32768, cvb + 256, F0h, F0l, F0r);
  conv(B1, F0h, F0l, F0r, B3, Sb(11));                                        // c6 -> B3
  k_pool<<<1024, 128, 0, stream>>>(B3, gptr, gbuf + 16384);

  k_head<<<4, 256, 0, stream>>>(gbuf, fcw, fcb, Wfc, bfc, bhw, bhb, Wcl, bcl, out);
}

// Round 7
// 1056.279 us; speedup vs baseline: 1.0790x; 1.0790x over previous
//
#include <hip/hip_runtime.h>

#define N_NODES 100000
#define NPAD    100032      // multiple of 64 for unguarded GEMM tiles
#define NBLK    1563        // NPAD/64
#define NEDGE   800000
#define NGRP    128
#define NSLOT   32          // mirrored stat-accumulator slots (atomic contention /32)
#define EPS     1e-5f

typedef unsigned int   u32;
typedef unsigned short u16;
typedef short bf16x8 __attribute__((ext_vector_type(8)));
typedef float f32x4  __attribute__((ext_vector_type(4)));

__device__ __forceinline__ float bf2f(u32 u){ return __uint_as_float(u << 16); }
__device__ __forceinline__ u16 f2bf(float f){
  u32 x = __float_as_uint(f);
  x += 0x7fffu + ((x >> 16) & 1u);      // round-to-nearest-even
  return (u16)(x >> 16);
}

// ---------------- preprocessing ----------------
__global__ void k_init(float* deg, int* cnt, int* fill, float* gbuf){
  int i = blockIdx.x * 256 + threadIdx.x;
  if (i < NPAD){ deg[i] = 1.0f; cnt[i] = 0; fill[i] = 0; }   // deg starts at 1 (self-loop)
  if (i < 4 * NGRP * 128) gbuf[i] = 0.f;
}

__global__ void k_deg(const int* __restrict__ col, const float* __restrict__ ew,
                      float* __restrict__ deg, int* __restrict__ cnt){
  int e = blockIdx.x * 256 + threadIdx.x;
  if (e < NEDGE){
    int c = col[e];
    atomicAdd(&deg[c], ew[e]);
    atomicAdd(&cnt[c], 1);
  }
}

__global__ void k_dinv(const float* __restrict__ deg, float* __restrict__ dinv, float* __restrict__ srow){
  int i = blockIdx.x * 256 + threadIdx.x;
  if (i < N_NODES){
    float d = deg[i];
    float v = d > 0.f ? rsqrtf(fmaxf(d, EPS)) : 0.f;
    dinv[i] = v; srow[i] = v * v;       // srow starts with self-loop norm
  }
}

__global__ __launch_bounds__(256) void k_chunksum(const int* __restrict__ cnt, int* __restrict__ csum){
  int b = blockIdx.x, t = threadIdx.x;
  int s = 0;
  for (int i = t; i < 1024; i += 256){ int idx = b * 1024 + i; if (idx < N_NODES) s += cnt[idx]; }
  __shared__ int red[256];
  red[t] = s; __syncthreads();
  for (int o = 128; o > 0; o >>= 1){ if (t < o) red[t] += red[t + o]; __syncthreads(); }
  if (t == 0) csum[b] = red[0];
}

__global__ __launch_bounds__(128) void k_chunkscan(const int* __restrict__ csum, int* __restrict__ coff,
                                                   int* __restrict__ ptrA){
  int t = threadIdx.x;
  __shared__ int s[128];
  int v = (t < 98) ? csum[t] : 0;
  s[t] = v; __syncthreads();
  for (int o = 1; o < 128; o <<= 1){
    int x = (t >= o) ? s[t - o] : 0;
    __syncthreads(); s[t] += x; __syncthreads();
  }
  if (t < 98) coff[t] = s[t] - v;       // exclusive chunk offsets
  if (t == 0) ptrA[N_NODES] = NEDGE;
}

__global__ __launch_bounds__(256) void k_scan2(const int* __restrict__ cnt, const int* __restrict__ coff,
                                               int* __restrict__ ptrA){
  int b = blockIdx.x, t = threadIdx.x;
  int base = b * 1024 + t * 4;
  int v[4], tot = 0;
  #pragma unroll
  for (int k = 0; k < 4; k++){ int idx = base + k; v[k] = (idx < N_NODES) ? cnt[idx] : 0; tot += v[k]; }
  __shared__ int sc[256];
  sc[t] = tot; __syncthreads();
  for (int o = 1; o < 256; o <<= 1){
    int x = (t >= o) ? sc[t - o] : 0;
    __syncthreads(); sc[t] += x; __syncthreads();
  }
  int off = coff[b] + sc[t] - tot;
  #pragma unroll
  for (int k = 0; k < 4; k++){ int idx = base + k; if (idx < N_NODES) ptrA[idx] = off; off += v[k]; }
}

// fill CSR + accumulate srow (merged, one edge pass)
__global__ void k_fill(const int* __restrict__ row, const int* __restrict__ col,
                       const float* __restrict__ ew, const float* __restrict__ dinv,
                       const int* __restrict__ ptrA, int* __restrict__ fill, int2* __restrict__ adj,
                       float* __restrict__ srow){
  int e = blockIdx.x * 256 + threadIdx.x;
  if (e < NEDGE){
    int r = row[e], c = col[e];
    float w = dinv[r] * ew[e] * dinv[c];
    int pos = ptrA[c] + atomicAdd(&fill[c], 1);
    adj[pos] = make_int2(r, __float_as_int(w));
    atomicAdd(&srow[c], w);
  }
}

// per-block LDS histogram -> partials (no global atomics)
__global__ __launch_bounds__(256) void k_bhist(const int* __restrict__ batch, int* __restrict__ bpart){
  __shared__ int loc[128];
  int t = threadIdx.x;
  if (t < 128) loc[t] = 0;
  __syncthreads();
  int i = blockIdx.x * 256 + t;
  if (i < N_NODES) atomicAdd(&loc[batch[i]], 1);
  __syncthreads();
  if (t < 128) bpart[blockIdx.x * 128 + t] = loc[t];
}

__global__ __launch_bounds__(128) void k_bscan(const int* __restrict__ bpart, int* __restrict__ gptr){
  int t = threadIdx.x;
  int v = 0;
  for (int p = 0; p < 391; p++) v += bpart[p * 128 + t];
  __shared__ int s[128];
  s[t] = v; __syncthreads();
  for (int o = 1; o < 128; o <<= 1){
    int x = (t >= o) ? s[t - o] : 0;
    __syncthreads(); s[t] += x; __syncthreads();
  }
  gptr[t + 1] = s[t];
  if (t == 0) gptr[0] = 0;
}

// ---------------- x (f32) -> bf16 staging + column stats (fused, one pass) ----------------
__global__ __launch_bounds__(256) void k_cvtstats(const float* __restrict__ x, u32* __restrict__ dst,
                                                  float* __restrict__ sums_out){
  __shared__ float R[1024];
  int t = threadIdx.x;
  float s0 = 0.f, q0 = 0.f, s1 = 0.f, q1 = 0.f;
  size_t base = (size_t)blockIdx.x * 4096 + t;
  #pragma unroll
  for (int it = 0; it < 16; it++){
    size_t idx = base + (size_t)it * 256;
    if (idx < (size_t)N_NODES * 64){
      float2 v = ((const float2*)x)[idx];
      dst[idx] = (u32)f2bf(v.x) | ((u32)f2bf(v.y) << 16);
      s0 += v.x; q0 += v.x * v.x; s1 += v.y; q1 += v.y * v.y;
    }
  }
  R[t] = s0; R[256 + t] = q0; R[512 + t] = s1; R[768 + t] = q1;
  __syncthreads();
  if (t < 64){
    float S0 = 0.f, Q0 = 0.f, S1 = 0.f, Q1 = 0.f;
    #pragma unroll
    for (int g = 0; g < 4; g++){
      S0 += R[g * 64 + t];       Q0 += R[256 + g * 64 + t];
      S1 += R[512 + g * 64 + t]; Q1 += R[768 + g * 64 + t];
    }
    float* so = sums_out + (blockIdx.x & (NSLOT - 1)) * 256;
    atomicAdd(&so[2 * t], S0);
    atomicAdd(&so[2 * t + 1], S1);
    atomicAdd(&so[128 + 2 * t], Q0);
    atomicAdd(&so[128 + 2 * t + 1], Q1);
  }
}

// ---------------- per-layer fold: BN into fragment-ordered hi/lo bf16 W + rank-one ----------------
__device__ __forceinline__ void fold_body(int blk, int t, const float* __restrict__ sums,
    const float* __restrict__ bw, const float* __restrict__ bb,
    const float* __restrict__ W, const float* __restrict__ bias,
    u16* __restrict__ Wh, u16* __restrict__ Wl, float* __restrict__ rb,
    float* scl, float* shf, float* stot, float* rred){
  {
    float s = 0.f;
    #pragma unroll 4
    for (int sl = 0; sl < NSLOT; sl++) s += sums[sl * 256 + t];
    stot[t] = s;
  }
  __syncthreads();
  if (t < 128){
    float mu  = stot[t] * (1.f / N_NODES);
    float var = stot[128 + t] * (1.f / N_NODES) - mu * mu;
    float sc  = bw[t] * rsqrtf(var + EPS);
    scl[t] = sc; shf[t] = bb[t] - mu * sc;
  }
  __syncthreads();
  {
    int idx = blk * 256 + t;
    int lane_ = idx & 63, sl = idx >> 6;   // sl = nt*4 + ks
    int nt_ = sl >> 2, ks_ = sl & 3;
    int n_ = nt_ * 16 + (lane_ & 15);
    int kb = ks_ * 32 + (lane_ >> 4) * 8;
    u16 hi8[8], lo8[8];
    #pragma unroll
    for (int j = 0; j < 8; j++){
      float wv = W[(kb + j) * 128 + n_];
      float xv = scl[kb + j] * wv;
      u16 hh = f2bf(xv);
      hi8[j] = hh; lo8[j] = f2bf(xv - bf2f(hh));
    }
    uint4 ph, pl;
    ph.x = (u32)hi8[0] | ((u32)hi8[1] << 16); ph.y = (u32)hi8[2] | ((u32)hi8[3] << 16);
    ph.z = (u32)hi8[4] | ((u32)hi8[5] << 16); ph.w = (u32)hi8[6] | ((u32)hi8[7] << 16);
    pl.x = (u32)lo8[0] | ((u32)lo8[1] << 16); pl.y = (u32)lo8[2] | ((u32)lo8[3] << 16);
    pl.z = (u32)lo8[4] | ((u32)lo8[5] << 16); pl.w = (u32)lo8[6] | ((u32)lo8[7] << 16);
    *(uint4*)&Wh[idx * 8] = ph;
    *(uint4*)&Wl[idx * 8] = pl;
  }
  {
    int nl = t & 15, kk = t >> 4;
    int n2 = blk * 16 + nl;
    float rp = 0.f;
    #pragma unroll
    for (int j = 0; j < 8; j++){
      int k2 = kk * 8 + j;
      rp += shf[k2] * W[k2 * 128 + n2];
    }
    rred[t] = rp;
  }
  __syncthreads();
  if (t < 16){
    float s = 0.f;
    #pragma unroll
    for (int kk2 = 0; kk2 < 16; kk2++) s += rred[kk2 * 16 + t];
    int n2 = blk * 16 + t;
    rb[n2] = s;
    rb[128 + n2] = bias[n2];
  }
}

__global__ __launch_bounds__(256) void k_fold(const float* __restrict__ sums,
    const float* __restrict__ bw, const float* __restrict__ bb,
    const float* __restrict__ W, const float* __restrict__ bias,
    u16* __restrict__ Wh, u16* __restrict__ Wl, float* __restrict__ rb){
  __shared__ float scl[128], shf[128], stot[256], rred[256];
  fold_body(blockIdx.x, threadIdx.x, sums, bw, bb, W, bias, Wh, Wl, rb, scl, shf, stot, rred);
}

__global__ __launch_bounds__(256) void k_fold2(
    const float* __restrict__ sumsA, const float* __restrict__ bwA, const float* __restrict__ bbA,
    const float* __restrict__ WA, const float* __restrict__ biasA,
    u16* __restrict__ WhA, u16* __restrict__ WlA, float* __restrict__ rbA,
    const float* __restrict__ sumsB, const float* __restrict__ bwB, const float* __restrict__ bbB,
    const float* __restrict__ WB, const float* __restrict__ biasB,
    u16* __restrict__ WhB, u16* __restrict__ WlB, float* __restrict__ rbB){
  __shared__ float scl[128], shf[128], stot[256], rred[256];
  int bb_ = blockIdx.x;
  if (bb_ < 8)
    fold_body(bb_, threadIdx.x, sumsA, bwA, bbA, WA, biasA, WhA, WlA, rbA, scl, shf, stot, rred);
  else
    fold_body(bb_ - 8, threadIdx.x, sumsB, bwB, bbB, WB, biasB, WhB, WlB, rbB, scl, shf, stot, rred);
}

// ---------------- epilogue macro: bias + rank-one + relu + store + slotted stats ----------------
#define CONV_EPILOGUE(RB, HOUT, SOUT, BLK)                                     \
  __syncthreads();                                                             \
  sred[t] = 0.f;                                                               \
  __syncthreads();                                                             \
  _Pragma("unroll")                                                            \
  for (int nt = 0; nt < 8; nt++){                                              \
    int colc = nt * 16 + m;                                                    \
    float rv = RB[colc], bv = RB[128 + colc];                                  \
    float s = 0.f, qq = 0.f;                                                   \
    _Pragma("unroll")                                                          \
    for (int r = 0; r < 4; r++){                                               \
      int rown = row0 + q * 4 + r;                                             \
      float v = C[nt][r] + srow[rown] * rv + bv;                               \
      v = fmaxf(v, 0.f);                                                       \
      u16 sv = f2bf(v);                                                        \
      HOUT[(size_t)rown * 128 + colc] = sv;                                    \
      if (rown < N_NODES){ float vv = bf2f(sv); s += vv; qq += vv * vv; }      \
    }                                                                          \
    s  += __shfl_xor(s, 16, 64);  s  += __shfl_xor(s, 32, 64);                 \
    qq += __shfl_xor(qq, 16, 64); qq += __shfl_xor(qq, 32, 64);                \
    if (q == 0){                                                               \
      atomicAdd(&sred[colc], s);                                               \
      atomicAdd(&sred[128 + colc], qq);                                        \
    }                                                                          \
  }                                                                            \
  __syncthreads();                                                             \
  atomicAdd(&SOUT[((BLK) & (NSLOT - 1)) * 256 + t], sred[t]);

#define FMA_KS(KS, V, WT) \
  acc[KS][0] += (WT) * __uint_as_float((V).x << 16); acc[KS][1] += (WT) * __uint_as_float((V).x & 0xffff0000u); \
  acc[KS][2] += (WT) * __uint_as_float((V).y << 16); acc[KS][3] += (WT) * __uint_as_float((V).y & 0xffff0000u); \
  acc[KS][4] += (WT) * __uint_as_float((V).z << 16); acc[KS][5] += (WT) * __uint_as_float((V).z & 0xffff0000u); \
  acc[KS][6] += (WT) * __uint_as_float((V).w << 16); acc[KS][7] += (WT) * __uint_as_float((V).w & 0xffff0000u);

#define VMCNT_2()  asm volatile("s_waitcnt vmcnt(2)" ::: "memory")
#define VMCNT_6()  asm volatile("s_waitcnt vmcnt(6)" ::: "memory")
#define VMCNT_10() asm volatile("s_waitcnt vmcnt(10)" ::: "memory")
#define VMCNT_11() asm volatile("s_waitcnt vmcnt(11)" ::: "memory")

// ---------------- LDS-staged gather: 3-stage global_load_lds rotation, 6-reg adj rotation ----------------
// Per GITER J: 5 vmcnt events (1 adj prefetch J+5, 4 stage loads for J+3).
// Waits derived from "events issued after target" (robust to older stragglers):
//   stage J has exactly 11 younger events -> vmcnt(11); adj J+3 has 10 -> vmcnt(10).
// Stage cover: 3 GITERs; adj-issue cover: 2 GITERs; adj-weight cover: ~5.
__device__ __forceinline__ void gll_stage(const u16* __restrict__ h, u16* dst, int2 aj, int lane){
  int c = lane & 15, g = lane >> 4;
  #pragma unroll
  for (int ii = 0; ii < 4; ii++){
    int rl = ii * 4 + g;
    int srcrow = __shfl(aj.x, rl, 64);
    const u16* src = h + (size_t)srcrow * 128 + (size_t)((c ^ rl) * 8);
    __builtin_amdgcn_global_load_lds((const void*)src, (void*)(dst + ii * 512), 16, 0, 0);
  }
}

#define GITER(WA_, WISS_, WD_, STG, J)                                         \
  WD_ = *(const int2*)(adj + base_ + min((J) + 5, dcl));                       \
  VMCNT_11();                                                                  \
  {                                                                            \
    float wgt = __int_as_float(__shfl((WA_).y, m, 64));                        \
    if ((J) < deg){                                                            \
      const u16* sp = stage + (STG) * 2048;                                    \
      _Pragma("unroll")                                                        \
      for (int ks = 0; ks < 4; ks++){                                          \
        int slot = (q + 4 * ks) ^ m;                                           \
        uint4 v = *(const uint4*)(sp + m * 128 + slot * 8);                    \
        FMA_KS(ks, v, wgt)                                                     \
      }                                                                        \
    }                                                                          \
  }                                                                            \
  VMCNT_10();                                                                  \
  gll_stage(h, stage + (STG) * 2048, WISS_, lane);

__device__ __forceinline__ void gather_row_lds(const u16* __restrict__ h,
    const int* __restrict__ ptrA, const int2* __restrict__ adj,
    const float* __restrict__ dinv, int row0, int lane, u16* stage,
    float (&acc)[4][8]){
  int m = lane & 15, q = lane >> 4;
  #pragma unroll
  for (int ks = 0; ks < 4; ks++)
    #pragma unroll
    for (int j = 0; j < 8; j++) acc[ks][j] = 0.f;
  int r = row0 + m;
  int r2 = min(r, N_NODES - 1);
  int b0 = ptrA[r2], b1 = ptrA[r2 + 1];
  int deg = (r < N_NODES) ? (b1 - b0) : 0;
  int base_ = min(b0, NEDGE - 1);
  int dcl = max(deg - 1, 0);
  float di = dinv[r2];
  float sw = (r < N_NODES) ? di * di : 0.f;
  // self-loop (registers; unconditional clamped loads)
  const u16* hq = h + q * 8;
  const u16* sp_ = hq + (size_t)r2 * 128;
  uint4 s0 = *(const uint4*)(sp_);
  uint4 s1 = *(const uint4*)(sp_ + 32);
  uint4 s2 = *(const uint4*)(sp_ + 64);
  uint4 s3 = *(const uint4*)(sp_ + 96);
  // wave-max degree (deg depends on m only; reduce over m-groups)
  int wmax = deg;
  wmax = max(wmax, __shfl_xor(wmax, 1, 64));
  wmax = max(wmax, __shfl_xor(wmax, 2, 64));
  wmax = max(wmax, __shfl_xor(wmax, 4, 64));
  wmax = max(wmax, __shfl_xor(wmax, 8, 64));
  FMA_KS(0, s0, sw) FMA_KS(1, s1, sw) FMA_KS(2, s2, sw) FMA_KS(3, s3, sw)
  if (wmax > 0){
    int2 W0 = *(const int2*)(adj + base_);
    int2 W1 = *(const int2*)(adj + base_ + min(1, dcl));
    int2 W2 = *(const int2*)(adj + base_ + min(2, dcl));
    int2 W3, W4, W5;
    VMCNT_2();                               // adj0 ready (events after W0-load: W1,W2)
    gll_stage(h, stage, W0, lane);           // stage slot0 = edge 0
    W3 = *(const int2*)(adj + base_ + min(3, dcl));
    VMCNT_6();                               // adj1 ready (after W1: W2,stage0(4),W3)
    gll_stage(h, stage + 2048, W1, lane);    // slot1 = edge 1
    W4 = *(const int2*)(adj + base_ + min(4, dcl));
    VMCNT_10();                              // adj2 ready (after W2: stage0,W3,stage1,W4)
    gll_stage(h, stage + 4096, W2, lane);    // slot2 = edge 2
    int j = 0;
    for (;;){
      GITER(W0, W3, W5, 0, j) if (++j >= wmax) break;
      GITER(W1, W4, W0, 1, j) if (++j >= wmax) break;
      GITER(W2, W5, W1, 2, j) if (++j >= wmax) break;
      GITER(W3, W0, W2, 0, j) if (++j >= wmax) break;
      GITER(W4, W1, W3, 1, j) if (++j >= wmax) break;
      GITER(W5, W2, W4, 2, j) if (++j >= wmax) break;
    }
  }
}

#define BUILD_AFRAG()                                                          \
  bf16x8 AH[4], AL[4];                                                         \
  _Pragma("unroll")                                                            \
  for (int ks = 0; ks < 4; ks++)                                               \
    _Pragma("unroll")                                                          \
    for (int j = 0; j < 8; j++){                                               \
      u16 hh = f2bf(acc[ks][j]);                                               \
      AH[ks][j] = (short)hh;                                                   \
      AL[ks][j] = (short)f2bf(acc[ks][j] - bf2f(hh));                          \
    }

#define MFMA_3PASS(WH, WL_)                                                    \
  _Pragma("unroll")                                                            \
  for (int ks = 0; ks < 4; ks++){                                              \
    _Pragma("unroll")                                                          \
    for (int nt = 0; nt < 8; nt++){                                            \
      bf16x8 bh = ((const bf16x8*)WH)[(nt * 4 + ks) * 64 + lane];              \
      bf16x8 bl = ((const bf16x8*)WL_)[(nt * 4 + ks) * 64 + lane];             \
      C[nt] = __builtin_amdgcn_mfma_f32_16x16x32_bf16(AH[ks], bh, C[nt], 0, 0, 0); \
      C[nt] = __builtin_amdgcn_mfma_f32_16x16x32_bf16(AL[ks], bh, C[nt], 0, 0, 0); \
      C[nt] = __builtin_amdgcn_mfma_f32_16x16x32_bf16(AH[ks], bl, C[nt], 0, 0, 0); \
    }                                                                          \
  }

// ---------------- fused conv: LDS-staged gather + MFMA (b-frags from global) + stats ----------------
__global__ __launch_bounds__(256, 3) void k_conv(
    const u16* __restrict__ h, const int* __restrict__ ptrA, const int2* __restrict__ adj,
    const float* __restrict__ dinv, const float* __restrict__ srow,
    const u16* __restrict__ Wh, const u16* __restrict__ Wl, const float* __restrict__ rb,
    u16* __restrict__ hout, float* __restrict__ sums_out){
  __shared__ u16 hstage[4][3][2048];
  __shared__ float sred[256];
  int t = threadIdx.x;
  int wave = t >> 6, lane = t & 63, m = lane & 15, q = lane >> 4;
  int blk = blockIdx.x;
  int row0 = blk * 64 + wave * 16;
  float acc[4][8];
  gather_row_lds(h, ptrA, adj, dinv, row0, lane, &hstage[wave][0][0], acc);
  BUILD_AFRAG()
  f32x4 C[8];
  #pragma unroll
  for (int nt = 0; nt < 8; nt++) C[nt] = f32x4{0.f, 0.f, 0.f, 0.f};
  MFMA_3PASS(Wh, Wl)
  CONV_EPILOGUE(rb, hout, sums_out, blk)
}

// ---------------- paired conv: two independent convs in one launch (grid 2*NBLK) ----------------
__global__ __launch_bounds__(256, 3) void k_conv2(
    const u16* __restrict__ hA, const u16* __restrict__ hB,
    const int* __restrict__ ptrA, const int2* __restrict__ adj,
    const float* __restrict__ dinv, const float* __restrict__ srow,
    const u16* __restrict__ WhA, const u16* __restrict__ WlA, const float* __restrict__ rbA,
    u16* __restrict__ houtA, float* __restrict__ sumsA,
    const u16* __restrict__ WhB, const u16* __restrict__ WlB, const float* __restrict__ rbB,
    u16* __restrict__ houtB, float* __restrict__ sumsB){
  __shared__ u16 hstage[4][3][2048];
  __shared__ float sred[256];
  int t = threadIdx.x;
  int wave = t >> 6, lane = t & 63, m = lane & 15, q = lane >> 4;
  int bb = blockIdx.x;
  int second = bb >= NBLK;
  int blk = second ? bb - NBLK : bb;
  const u16* h = second ? hB : hA;
  const u16* Wh = second ? WhB : WhA;
  const u16* Wl = second ? WlB : WlA;
  const float* rb = second ? rbB : rbA;
  u16* hout = second ? houtB : houtA;
  float* sums_out = second ? sumsB : sumsA;
  int row0 = blk * 64 + wave * 16;
  float acc[4][8];
  gather_row_lds(h, ptrA, adj, dinv, row0, lane, &hstage[wave][0][0], acc);
  BUILD_AFRAG()
  f32x4 C[8];
  #pragma unroll
  for (int nt = 0; nt < 8; nt++) C[nt] = f32x4{0.f, 0.f, 0.f, 0.f};
  MFMA_3PASS(Wh, Wl)
  CONV_EPILOGUE(rb, hout, sums_out, blk)
}

// ---------------- dual conv: one gather, two folded-W phases (a2 & c2 share S@a1) ----------------
__global__ __launch_bounds__(256, 3) void k_dualconv(
    const u16* __restrict__ h, const int* __restrict__ ptrA, const int2* __restrict__ adj,
    const float* __restrict__ dinv, const float* __restrict__ srow,
    const u16* __restrict__ Wh1, const u16* __restrict__ Wl1, const float* __restrict__ rb1,
    u16* __restrict__ hout1, float* __restrict__ sums1,
    const u16* __restrict__ Wh2, const u16* __restrict__ Wl2, const float* __restrict__ rb2,
    u16* __restrict__ hout2, float* __restrict__ sums2){
  __shared__ u16 hstage[4][3][2048];
  __shared__ float sred[256];
  int t = threadIdx.x;
  int wave = t >> 6, lane = t & 63, m = lane & 15, q = lane >> 4;
  int blk = blockIdx.x;
  int row0 = blk * 64 + wave * 16;
  float acc[4][8];
  gather_row_lds(h, ptrA, adj, dinv, row0, lane, &hstage[wave][0][0], acc);
  BUILD_AFRAG()
  f32x4 C[8];
  #pragma unroll
  for (int nt = 0; nt < 8; nt++) C[nt] = f32x4{0.f, 0.f, 0.f, 0.f};
  MFMA_3PASS(Wh1, Wl1)
  CONV_EPILOGUE(rb1, hout1, sums1, blk)
  #pragma unroll
  for (int nt = 0; nt < 8; nt++) C[nt] = f32x4{0.f, 0.f, 0.f, 0.f};
  MFMA_3PASS(Wh2, Wl2)
  CONV_EPILOGUE(rb2, hout2, sums2, blk)
}

// ---------------- branch-4 elementwise: out = relu(bn(h)); slotted stats (uint2 = 8B/lane) ----------------
__global__ __launch_bounds__(256) void k_normrelu(const u16* __restrict__ h, const float* __restrict__ sums,
    const float* __restrict__ bw, const float* __restrict__ bb, u16* __restrict__ o,
    float* __restrict__ sums_out){
  __shared__ float scl[128], shf[128], R[2048], stot[256];
  int t = threadIdx.x;
  {
    float s = 0.f;
    #pragma unroll 4
    for (int sl = 0; sl < NSLOT; sl++) s += sums[sl * 256 + t];
    stot[t] = s;
  }
  __syncthreads();
  if (t < 128){
    float mu  = stot[t] * (1.f / N_NODES);
    float var = stot[128 + t] * (1.f / N_NODES) - mu * mu;
    float sc  = bw[t] * rsqrtf(var + EPS);
    scl[t] = sc; shf[t] = bb[t] - mu * sc;
  }
  __syncthreads();
  int c0 = (t & 31) * 4;
  float sc0 = scl[c0], sh0 = shf[c0], sc1 = scl[c0 + 1], sh1 = shf[c0 + 1];
  float sc2 = scl[c0 + 2], sh2 = shf[c0 + 2], sc3 = scl[c0 + 3], sh3 = shf[c0 + 3];
  float s0 = 0.f, q0 = 0.f, s1 = 0.f, q1 = 0.f, s2 = 0.f, q2 = 0.f, s3 = 0.f, q3 = 0.f;
  size_t base = (size_t)blockIdx.x * 2048 + t;
  #pragma unroll
  for (int it = 0; it < 8; it++){
    size_t idx = base + (size_t)it * 256;
    if (idx < (size_t)N_NODES * 32){
      uint2 v = ((const uint2*)h)[idx];
      float x0 = fmaxf(bf2f(v.x & 0xffffu) * sc0 + sh0, 0.f);
      float x1 = fmaxf(bf2f(v.x >> 16) * sc1 + sh1, 0.f);
      float x2 = fmaxf(bf2f(v.y & 0xffffu) * sc2 + sh2, 0.f);
      float x3 = fmaxf(bf2f(v.y >> 16) * sc3 + sh3, 0.f);
      u16 r0 = f2bf(x0), r1 = f2bf(x1), r2 = f2bf(x2), r3 = f2bf(x3);
      uint2 w;
      w.x = (u32)r0 | ((u32)r1 << 16);
      w.y = (u32)r2 | ((u32)r3 << 16);
      ((uint2*)o)[idx] = w;
      float y0 = bf2f(r0), y1 = bf2f(r1), y2 = bf2f(r2), y3 = bf2f(r3);
      s0 += y0; q0 += y0 * y0; s1 += y1; q1 += y1 * y1;
      s2 += y2; q2 += y2 * y2; s3 += y3; q3 += y3 * y3;
    }
  }
  R[t] = s0; R[256 + t] = s1; R[512 + t] = s2; R[768 + t] = s3;
  R[1024 + t] = q0; R[1280 + t] = q1; R[1536 + t] = q2; R[1792 + t] = q3;
  __syncthreads();
  if (t < 128){
    int j = t & 3, l = t >> 2;           // col t = l*4 + j handled by threads th: th&31==l
    float S = 0.f, Q = 0.f;
    #pragma unroll
    for (int g = 0; g < 8; g++){
      int th = l + 32 * g;
      S += R[j * 256 + th];
      Q += R[1024 + j * 256 + th];
    }
    float* so = sums_out + (blockIdx.x & (NSLOT - 1)) * 256;
    atomicAdd(&so[t], S);
    atomicAdd(&so[128 + t], Q);
  }
}

// ---------------- global_add_pool: uint4 16B/lane, shfl row-reduce ----------------
__global__ __launch_bounds__(128) void k_pool(const u16* __restrict__ h, const int* __restrict__ gptr,
                                              float* __restrict__ gdst){
  __shared__ float part[2][16][8];
  int g = blockIdx.x >> 3, s = blockIdx.x & 7, t = threadIdx.x;
  int cc = t & 15, rr = t >> 4, wv = t >> 6, rrw = rr & 3;
  int b = gptr[g], e = gptr[g + 1];
  int len = e - b, per = (len + 7) >> 3;
  int r0 = b + s * per, r1 = min(r0 + per, e);
  float a[8] = {0.f, 0.f, 0.f, 0.f, 0.f, 0.f, 0.f, 0.f};
  for (int r = r0 + rr; r < r1; r += 8){
    uint4 v = *(const uint4*)(h + (size_t)r * 128 + cc * 8);
    a[0] += bf2f(v.x & 0xffffu); a[1] += bf2f(v.x >> 16);
    a[2] += bf2f(v.y & 0xffffu); a[3] += bf2f(v.y >> 16);
    a[4] += bf2f(v.z & 0xffffu); a[5] += bf2f(v.z >> 16);
    a[6] += bf2f(v.w & 0xffffu); a[7] += bf2f(v.w >> 16);
  }
  #pragma unroll
  for (int j = 0; j < 8; j++){
    a[j] += __shfl_xor(a[j], 16, 64);
    a[j] += __shfl_xor(a[j], 32, 64);
  }
  if (rrw == 0){
    #pragma unroll
    for (int j = 0; j < 8; j++) part[wv][cc][j] = a[j];
  }
  __syncthreads();
  {
    float sum = part[0][t >> 3][t & 7] + part[1][t >> 3][t & 7];
    atomicAdd(&gdst[g * 128 + t], sum);
  }
}

// ---------------- head: 8x8 register-tile FC, shfl-reduced classifier ----------------
__global__ __launch_bounds__(256) void k_head(const float* __restrict__ gbuf,
    const float* __restrict__ fcw, const float* __restrict__ fcb,
    const float* __restrict__ Wfc, const float* __restrict__ bfc,
    const float* __restrict__ bhw, const float* __restrict__ bhb,
    const float* __restrict__ Wcl, const float* __restrict__ bcl,
    float* __restrict__ out){
  __shared__ float GS[128 * 65];           // Gbn k-half staging (33 KB)
  __shared__ float ls[256], lq[256];
  __shared__ float scl[128], shf[128], scl2[128], shf2[128];
  __shared__ float sumT[128], sumQ[128];
  __shared__ float WclT[1280], Lrow[1280];
  int t = threadIdx.x, br = blockIdx.x;
  int slot = (br == 1) ? 1 : (br == 3 ? 3 : 0);   // branch3 == branch1 (slot 0)
  const float* G = gbuf + slot * 16384;
  { // stats of G
    int col = t & 127, hf2 = t >> 7;
    float s = 0.f, q = 0.f;
    for (int g = hf2 * 64; g < hf2 * 64 + 64; g++){ float v = G[g * 128 + col]; s += v; q += v * v; }
    ls[t] = s; lq[t] = q;
  }
  for (int idx = t; idx < 1280; idx += 256){     // WclT[cc][c] = Wcl[c][cc]
    int cc = idx >> 7, c = idx & 127;
    WclT[idx] = Wcl[c * 10 + cc];
  }
  if (t < 128){ sumT[t] = 0.f; sumQ[t] = 0.f; }
  __syncthreads();
  if (t < 128){
    float s = ls[t] + ls[t + 128], q = lq[t] + lq[t + 128];
    float mu = s * (1.f / 128), var = q * (1.f / 128) - mu * mu;
    float sc = fcw[t] * rsqrtf(var + EPS);
    scl[t] = sc; shf[t] = fcb[t] - mu * sc;
  }
  __syncthreads();
  int tr = t >> 4, tc = t & 15, r0 = tr * 8, c0 = tc * 8;
  float acc[8][8];
  #pragma unroll
  for (int a = 0; a < 8; a++)
    #pragma unroll
    for (int b = 0; b < 8; b++) acc[a][b] = 0.f;
  for (int kh = 0; kh < 2; kh++){
    for (int idx = t; idx < 8192; idx += 256){
      int r = idx >> 6, kk = idx & 63, f = kh * 64 + kk;
      GS[r * 65 + kk] = G[r * 128 + f] * scl[f] + shf[f];
    }
    __syncthreads();
    #pragma unroll 2
    for (int k = 0; k < 64; k++){
      float a[8];
      #pragma unroll
      for (int ri = 0; ri < 8; ri++) a[ri] = GS[(r0 + ri) * 65 + k];
      float4 b0 = *(const float4*)&Wfc[(kh * 64 + k) * 128 + c0];
      float4 b1 = *(const float4*)&Wfc[(kh * 64 + k) * 128 + c0 + 4];
      float bb[8] = {b0.x, b0.y, b0.z, b0.w, b1.x, b1.y, b1.z, b1.w};
      #pragma unroll
      for (int ri = 0; ri < 8; ri++)
        #pragma unroll
        for (int ci = 0; ci < 8; ci++) acc[ri][ci] += a[ri] * bb[ci];
    }
    __syncthreads();
  }
  #pragma unroll
  for (int ci = 0; ci < 8; ci++){
    float bb = bfc[c0 + ci];
    float s = 0.f, q = 0.f;
    #pragma unroll
    for (int ri = 0; ri < 8; ri++){
      float v = fmaxf(acc[ri][ci] + bb, 0.f);
      acc[ri][ci] = v; s += v; q += v * v;
    }
    atomicAdd(&sumT[c0 + ci], s);
    atomicAdd(&sumQ[c0 + ci], q);
  }
  __syncthreads();
  if (t < 128){
    float mu = sumT[t] * (1.f / 128), var = sumQ[t] * (1.f / 128) - mu * mu;
    float sc = bhw[t] * rsqrtf(var + EPS);
    scl2[t] = sc; shf2[t] = bhb[t] - mu * sc;
  }
  __syncthreads();
  #pragma unroll
  for (int ci = 0; ci < 8; ci++){
    float sc = scl2[c0 + ci], sh = shf2[c0 + ci];
    #pragma unroll
    for (int ri = 0; ri < 8; ri++) acc[ri][ci] = acc[ri][ci] * sc + sh;
  }
  #pragma unroll
  for (int ri = 0; ri < 8; ri++){
    float pl[10];
    #pragma unroll
    for (int cc = 0; cc < 10; cc++) pl[cc] = 0.f;
    #pragma unroll
    for (int ci = 0; ci < 8; ci++){
      float v = acc[ri][ci];
      #pragma unroll
      for (int cc = 0; cc < 10; cc++) pl[cc] += v * WclT[cc * 128 + c0 + ci];
    }
    #pragma unroll
    for (int msk = 1; msk < 16; msk <<= 1)
      #pragma unroll
      for (int cc = 0; cc < 10; cc++) pl[cc] += __shfl_xor(pl[cc], msk, 64);
    if (tc == 0)
      #pragma unroll
      for (int cc = 0; cc < 10; cc++) Lrow[(r0 + ri) * 10 + cc] = pl[cc];
  }
  __syncthreads();
  if (t < 128){
    float l[10];
    #pragma unroll
    for (int cc = 0; cc < 10; cc++) l[cc] = Lrow[t * 10 + cc] + bcl[cc];
    float m = l[0];
    #pragma unroll
    for (int cc = 1; cc < 10; cc++) m = fmaxf(m, l[cc]);
    float se = 0.f;
    #pragma unroll
    for (int cc = 0; cc < 10; cc++) se += expf(l[cc] - m);
    float lse = m + logf(se);
    #pragma unroll
    for (int cc = 0; cc < 10; cc++) out[br * 1280 + t * 10 + cc] = l[cc] - lse;
  }
}

extern "C" void kernel_launch(void* const* d_in, const int* in_sizes, int n_in,
                              void* d_out, int out_size, void* d_ws, size_t ws_size,
                              hipStream_t stream){
  const float* x    = (const float*)d_in[0];
  const int*  ei    = (const int*)d_in[1];      // [2,E]: rows then cols
  const int*  batch = (const int*)d_in[2];
  const float* ew   = (const float*)d_in[3];
  const float* bnfw = (const float*)d_in[4];
  const float* bnfb = (const float*)d_in[5];
  const float* cfW  = (const float*)d_in[6];
  const float* cfb  = (const float*)d_in[7];
  const float* bnsw = (const float*)d_in[8];
  const float* bnsb = (const float*)d_in[9];
  const float* cvW  = (const float*)d_in[10];
  const float* cvb  = (const float*)d_in[11];
  const float* fcw  = (const float*)d_in[12];
  const float* fcb  = (const float*)d_in[13];
  const float* Wfc  = (const float*)d_in[14];
  const float* bfc  = (const float*)d_in[15];
  const float* bhw  = (const float*)d_in[16];
  const float* bhb  = (const float*)d_in[17];
  const float* Wcl  = (const float*)d_in[18];
  const float* bcl  = (const float*)d_in[19];
  float* out = (float*)d_out;

  char* p = (char*)d_ws;
  auto carve = [&](size_t bytes)->void*{ void* r = (void*)p; p += (bytes + 255) & ~(size_t)255; return r; };
  float* deg  = (float*)carve((size_t)NPAD * 4);
  float* dinv = (float*)carve((size_t)NPAD * 4);
  float* srow = (float*)carve((size_t)NPAD * 4);
  int*   cnt  = (int*)carve((size_t)NPAD * 4);
  int*   fill = (int*)carve((size_t)NPAD * 4);
  int*   ptrA = (int*)carve((size_t)(NPAD + 1) * 4);
  int*   bpart= (int*)carve((size_t)391 * 128 * 4);
  int*   csum = (int*)carve(512);
  int*   coff = (int*)carve(512);
  int*   gptr = (int*)carve(1024);
  float* S    = (float*)carve((size_t)13 * NSLOT * 1024);   // 13 steps x NSLOT x 256 floats
  float* gbuf = (float*)carve(4 * 128 * 128 * 4);
  u16*   F0h  = (u16*)carve(32768);  u16* F0l = (u16*)carve(32768);  float* F0r = (float*)carve(1024);
  u16*   F1h  = (u16*)carve(32768);  u16* F1l = (u16*)carve(32768);  float* F1r = (float*)carve(1024);
  u16*   F2h  = (u16*)carve(32768);  u16* F2l = (u16*)carve(32768);  float* F2r = (float*)carve(1024);
  u16*   B0   = (u16*)carve((size_t)NPAD * 256);
  u16*   B1   = (u16*)carve((size_t)NPAD * 256);
  u16*   B2   = (u16*)carve((size_t)NPAD * 256);
  u16*   B3   = (u16*)carve((size_t)NPAD * 256);
  int2*  adj  = (int2*)carve((size_t)NEDGE * 8);
  u16*   Xb   = B3;   // bf16 x staging; B3's first real write (d2) is after L0 conv consumes Xb
  auto Sb = [&](int i){ return S + (size_t)i * NSLOT * 256; };

  (void)hipMemsetAsync(S, 0, (size_t)13 * NSLOT * 1024, stream);

  // preprocessing: degrees, norms, CSR, group offsets
  k_init<<<392, 256, 0, stream>>>(deg, cnt, fill, gbuf);
  k_deg<<<3125, 256, 0, stream>>>(ei + NEDGE, ew, deg, cnt);
  k_dinv<<<391, 256, 0, stream>>>(deg, dinv, srow);
  k_chunksum<<<98, 256, 0, stream>>>(cnt, csum);
  k_chunkscan<<<1, 128, 0, stream>>>(csum, coff, ptrA);
  k_scan2<<<98, 256, 0, stream>>>(cnt, coff, ptrA);
  k_fill<<<3125, 256, 0, stream>>>(ei, ei + NEDGE, ew, dinv, ptrA, fill, adj, srow);
  k_bhist<<<391, 256, 0, stream>>>(batch, bpart);
  k_bscan<<<1, 128, 0, stream>>>(bpart, gptr);
  k_cvtstats<<<NBLK, 256, 0, stream>>>(x, (u32*)Xb, Sb(0));

  auto fold = [&](const float* Sin, const float* bw, const float* bb,
                  const float* W, const float* bias, u16* Fh, u16* Fl, float* Fr){
    k_fold<<<8, 256, 0, stream>>>(Sin, bw, bb, W, bias, Fh, Fl, Fr);
  };
  auto conv = [&](const u16* hin, const u16* Fh, const u16* Fl, const float* Fr,
                  u16* hout, float* Sout){
    k_conv<<<NBLK, 256, 0, stream>>>(hin, ptrA, adj, dinv, srow, Fh, Fl, Fr, hout, Sout);
  };

  // L0: h_init = relu(conv(bn_feat(x)))
  fold(Sb(0), bnfw, bnfb, cfW, cfb, F0h, F0l, F0r);
  conv(Xb, F0h, F0l, F0r, B0, Sb(1));                                         // B0 = h_init
  // a1 = step(h_init, bn0/W0)  (== branch2 c1)
  fold(Sb(1), bnsw, bnsb, cvW, cvb, F1h, F1l, F1r);
  conv(B0, F1h, F1l, F1r, B1, Sb(2));                                         // B1 = a1
  // branch 4: d1,d2,d3 (d1 uses stats(h_init))
  k_normrelu<<<NBLK, 256, 0, stream>>>(B0, Sb(1), bnsw,       bnsb,       B2, Sb(3));   // d1 -> B2
  k_normrelu<<<NBLK, 256, 0, stream>>>(B2, Sb(3), bnsw + 128, bnsb + 128, B3, Sb(4));   // d2 -> B3
  k_normrelu<<<NBLK, 256, 0, stream>>>(B3, Sb(4), bnsw + 256, bnsb + 256, B2, Sb(12));  // d3 -> B2
  k_pool<<<1024, 128, 0, stream>>>(B2, gptr, gbuf + 3 * 16384);
  // dual: a2 = step(a1, bn1/W1), c2 = step(a1, bn0/W0) — one gather of S@a1; both folds one launch
  k_fold2<<<16, 256, 0, stream>>>(
      Sb(2), bnsw + 128, bnsb + 128, cvW + 16384, cvb + 128, F0h, F0l, F0r,
      Sb(2), bnsw,       bnsb,       cvW,         cvb,       F1h, F1l, F1r);
  k_dualconv<<<NBLK, 256, 0, stream>>>(B1, ptrA, adj, dinv, srow,
      F0h, F0l, F0r, B3, Sb(5),       // a2 -> B3
      F1h, F1l, F1r, B2, Sb(6));      // c2 -> B2
  // a3 = step(a2, bn2/W2) -> branches 1 & 3 ; c3 = step(c2, bn1/W1) — independent, one launch
  k_fold2<<<16, 256, 0, stream>>>(
      Sb(5), bnsw + 256, bnsb + 256, cvW + 32768, cvb + 256, F2h, F2l, F2r,
      Sb(6), bnsw + 128, bnsb + 128, cvW + 16384, cvb + 128, F0h, F0l, F0r);
  k_conv2<<<2 * NBLK, 256, 0, stream>>>(B3, B2, ptrA, adj, dinv, srow,
      F2h, F2l, F2r, B0, Sb(10),      // a3 -> B0
      F0h, F0l, F0r, B1, Sb(7));      // c3 -> B1
  k_pool<<<1024, 128, 0, stream>>>(B0, gptr, gbuf);
  // c4 = step(c3, bn1/W1)
  fold(Sb(7), bnsw + 128, bnsb + 128, cvW + 16384, cvb + 128, F1h, F1l, F1r);
  conv(B1, F1h, F1l, F1r, B2, Sb(8));                                         // c4 -> B2
  // c5 = step(c4, bn2/W2)
  fold(Sb(8), bnsw + 256, bnsb + 256, cvW + 32768, cvb + 256, F2h, F2l, F2r);
  conv(B2, F2h, F2l, F2r, B1, Sb(9));                                         // c5 -> B1
  // c6 = step(c5, bn2/W2) -> branch 2
  fold(Sb(9), bnsw + 256, bnsb + 256, cvW + 32768, cvb + 256, F0h, F0l, F0r);
  conv(B1, F0h, F0l, F0r, B3, Sb(11));                                        // c6 -> B3
  k_pool<<<1024, 128, 0, stream>>>(B3, gptr, gbuf + 16384);

  k_head<<<4, 256, 0, stream>>>(gbuf, fcw, fcb, Wfc, bfc, bhw, bhb, Wcl, bcl, out);
}

// Round 8
// 988.404 us; speedup vs baseline: 1.1531x; 1.0687x over previous
//
#include <hip/hip_runtime.h>

#define N_NODES 100000
#define NPAD    100032      // multiple of 64 for unguarded GEMM tiles
#define NBLK    1563        // NPAD/64
#define NEDGE   800000
#define NGRP    128
#define NSLOT   32          // mirrored stat-accumulator slots (atomic contention /32)
#define EPS     1e-5f

typedef unsigned int   u32;
typedef unsigned short u16;
typedef short bf16x8 __attribute__((ext_vector_type(8)));
typedef float f32x4  __attribute__((ext_vector_type(4)));

__device__ __forceinline__ float bf2f(u32 u){ return __uint_as_float(u << 16); }
__device__ __forceinline__ u16 f2bf(float f){
  u32 x = __float_as_uint(f);
  x += 0x7fffu + ((x >> 16) & 1u);      // round-to-nearest-even
  return (u16)(x >> 16);
}

// ---------------- preprocessing ----------------
__global__ void k_init(float* deg, int* cnt, int* fill, float* gbuf){
  int i = blockIdx.x * 256 + threadIdx.x;
  if (i < NPAD){ deg[i] = 1.0f; cnt[i] = 0; fill[i] = 0; }   // deg starts at 1 (self-loop)
  if (i < 4 * NGRP * 128) gbuf[i] = 0.f;
}

__global__ void k_deg(const int* __restrict__ col, const float* __restrict__ ew,
                      float* __restrict__ deg, int* __restrict__ cnt){
  int e = blockIdx.x * 256 + threadIdx.x;
  if (e < NEDGE){
    int c = col[e];
    atomicAdd(&deg[c], ew[e]);
    atomicAdd(&cnt[c], 1);
  }
}

__global__ void k_dinv(const float* __restrict__ deg, float* __restrict__ dinv, float* __restrict__ srow){
  int i = blockIdx.x * 256 + threadIdx.x;
  if (i < N_NODES){
    float d = deg[i];
    float v = d > 0.f ? rsqrtf(fmaxf(d, EPS)) : 0.f;
    dinv[i] = v; srow[i] = v * v;       // srow starts with self-loop norm
  }
}

__global__ __launch_bounds__(256) void k_chunksum(const int* __restrict__ cnt, int* __restrict__ csum){
  int b = blockIdx.x, t = threadIdx.x;
  int s = 0;
  for (int i = t; i < 1024; i += 256){ int idx = b * 1024 + i; if (idx < N_NODES) s += cnt[idx]; }
  __shared__ int red[256];
  red[t] = s; __syncthreads();
  for (int o = 128; o > 0; o >>= 1){ if (t < o) red[t] += red[t + o]; __syncthreads(); }
  if (t == 0) csum[b] = red[0];
}

__global__ __launch_bounds__(128) void k_chunkscan(const int* __restrict__ csum, int* __restrict__ coff,
                                                   int* __restrict__ ptrA){
  int t = threadIdx.x;
  __shared__ int s[128];
  int v = (t < 98) ? csum[t] : 0;
  s[t] = v; __syncthreads();
  for (int o = 1; o < 128; o <<= 1){
    int x = (t >= o) ? s[t - o] : 0;
    __syncthreads(); s[t] += x; __syncthreads();
  }
  if (t < 98) coff[t] = s[t] - v;       // exclusive chunk offsets
  if (t == 0) ptrA[N_NODES] = NEDGE;
}

__global__ __launch_bounds__(256) void k_scan2(const int* __restrict__ cnt, const int* __restrict__ coff,
                                               int* __restrict__ ptrA){
  int b = blockIdx.x, t = threadIdx.x;
  int base = b * 1024 + t * 4;
  int v[4], tot = 0;
  #pragma unroll
  for (int k = 0; k < 4; k++){ int idx = base + k; v[k] = (idx < N_NODES) ? cnt[idx] : 0; tot += v[k]; }
  __shared__ int sc[256];
  sc[t] = tot; __syncthreads();
  for (int o = 1; o < 256; o <<= 1){
    int x = (t >= o) ? sc[t - o] : 0;
    __syncthreads(); sc[t] += x; __syncthreads();
  }
  int off = coff[b] + sc[t] - tot;
  #pragma unroll
  for (int k = 0; k < 4; k++){ int idx = base + k; if (idx < N_NODES) ptrA[idx] = off; off += v[k]; }
}

// fill CSR + accumulate srow (merged, one edge pass)
__global__ void k_fill(const int* __restrict__ row, const int* __restrict__ col,
                       const float* __restrict__ ew, const float* __restrict__ dinv,
                       const int* __restrict__ ptrA, int* __restrict__ fill, int2* __restrict__ adj,
                       float* __restrict__ srow){
  int e = blockIdx.x * 256 + threadIdx.x;
  if (e < NEDGE){
    int r = row[e], c = col[e];
    float w = dinv[r] * ew[e] * dinv[c];
    int pos = ptrA[c] + atomicAdd(&fill[c], 1);
    adj[pos] = make_int2(r, __float_as_int(w));
    atomicAdd(&srow[c], w);
  }
}

// per-block LDS histogram -> partials (no global atomics)
__global__ __launch_bounds__(256) void k_bhist(const int* __restrict__ batch, int* __restrict__ bpart){
  __shared__ int loc[128];
  int t = threadIdx.x;
  if (t < 128) loc[t] = 0;
  __syncthreads();
  int i = blockIdx.x * 256 + t;
  if (i < N_NODES) atomicAdd(&loc[batch[i]], 1);
  __syncthreads();
  if (t < 128) bpart[blockIdx.x * 128 + t] = loc[t];
}

__global__ __launch_bounds__(128) void k_bscan(const int* __restrict__ bpart, int* __restrict__ gptr){
  int t = threadIdx.x;
  int v = 0;
  for (int p = 0; p < 391; p++) v += bpart[p * 128 + t];
  __shared__ int s[128];
  s[t] = v; __syncthreads();
  for (int o = 1; o < 128; o <<= 1){
    int x = (t >= o) ? s[t - o] : 0;
    __syncthreads(); s[t] += x; __syncthreads();
  }
  gptr[t + 1] = s[t];
  if (t == 0) gptr[0] = 0;
}

// ---------------- x (f32) -> bf16 staging + column stats (fused, one pass) ----------------
__global__ __launch_bounds__(256) void k_cvtstats(const float* __restrict__ x, u32* __restrict__ dst,
                                                  float* __restrict__ sums_out){
  __shared__ float R[1024];
  int t = threadIdx.x;
  float s0 = 0.f, q0 = 0.f, s1 = 0.f, q1 = 0.f;
  size_t base = (size_t)blockIdx.x * 4096 + t;
  #pragma unroll
  for (int it = 0; it < 16; it++){
    size_t idx = base + (size_t)it * 256;
    if (idx < (size_t)N_NODES * 64){
      float2 v = ((const float2*)x)[idx];
      dst[idx] = (u32)f2bf(v.x) | ((u32)f2bf(v.y) << 16);
      s0 += v.x; q0 += v.x * v.x; s1 += v.y; q1 += v.y * v.y;
    }
  }
  R[t] = s0; R[256 + t] = q0; R[512 + t] = s1; R[768 + t] = q1;
  __syncthreads();
  if (t < 64){
    float S0 = 0.f, Q0 = 0.f, S1 = 0.f, Q1 = 0.f;
    #pragma unroll
    for (int g = 0; g < 4; g++){
      S0 += R[g * 64 + t];       Q0 += R[256 + g * 64 + t];
      S1 += R[512 + g * 64 + t]; Q1 += R[768 + g * 64 + t];
    }
    float* so = sums_out + (blockIdx.x & (NSLOT - 1)) * 256;
    atomicAdd(&so[2 * t], S0);
    atomicAdd(&so[2 * t + 1], S1);
    atomicAdd(&so[128 + 2 * t], Q0);
    atomicAdd(&so[128 + 2 * t + 1], Q1);
  }
}

// ---------------- per-layer fold: BN into fragment-ordered hi/lo bf16 W + rank-one ----------------
__device__ __forceinline__ void fold_body(int blk, int t, const float* __restrict__ sums,
    const float* __restrict__ bw, const float* __restrict__ bb,
    const float* __restrict__ W, const float* __restrict__ bias,
    u16* __restrict__ Wh, u16* __restrict__ Wl, float* __restrict__ rb,
    float* scl, float* shf, float* stot, float* rred){
  {
    float s = 0.f;
    #pragma unroll 4
    for (int sl = 0; sl < NSLOT; sl++) s += sums[sl * 256 + t];
    stot[t] = s;
  }
  __syncthreads();
  if (t < 128){
    float mu  = stot[t] * (1.f / N_NODES);
    float var = stot[128 + t] * (1.f / N_NODES) - mu * mu;
    float sc  = bw[t] * rsqrtf(var + EPS);
    scl[t] = sc; shf[t] = bb[t] - mu * sc;
  }
  __syncthreads();
  {
    int idx = blk * 256 + t;
    int lane_ = idx & 63, sl = idx >> 6;   // sl = nt*4 + ks
    int nt_ = sl >> 2, ks_ = sl & 3;
    int n_ = nt_ * 16 + (lane_ & 15);
    int kb = ks_ * 32 + (lane_ >> 4) * 8;
    u16 hi8[8], lo8[8];
    #pragma unroll
    for (int j = 0; j < 8; j++){
      float wv = W[(kb + j) * 128 + n_];
      float xv = scl[kb + j] * wv;
      u16 hh = f2bf(xv);
      hi8[j] = hh; lo8[j] = f2bf(xv - bf2f(hh));
    }
    uint4 ph, pl;
    ph.x = (u32)hi8[0] | ((u32)hi8[1] << 16); ph.y = (u32)hi8[2] | ((u32)hi8[3] << 16);
    ph.z = (u32)hi8[4] | ((u32)hi8[5] << 16); ph.w = (u32)hi8[6] | ((u32)hi8[7] << 16);
    pl.x = (u32)lo8[0] | ((u32)lo8[1] << 16); pl.y = (u32)lo8[2] | ((u32)lo8[3] << 16);
    pl.z = (u32)lo8[4] | ((u32)lo8[5] << 16); pl.w = (u32)lo8[6] | ((u32)lo8[7] << 16);
    *(uint4*)&Wh[idx * 8] = ph;
    *(uint4*)&Wl[idx * 8] = pl;
  }
  {
    int nl = t & 15, kk = t >> 4;
    int n2 = blk * 16 + nl;
    float rp = 0.f;
    #pragma unroll
    for (int j = 0; j < 8; j++){
      int k2 = kk * 8 + j;
      rp += shf[k2] * W[k2 * 128 + n2];
    }
    rred[t] = rp;
  }
  __syncthreads();
  if (t < 16){
    float s = 0.f;
    #pragma unroll
    for (int kk2 = 0; kk2 < 16; kk2++) s += rred[kk2 * 16 + t];
    int n2 = blk * 16 + t;
    rb[n2] = s;
    rb[128 + n2] = bias[n2];
  }
}

__global__ __launch_bounds__(256) void k_fold(const float* __restrict__ sums,
    const float* __restrict__ bw, const float* __restrict__ bb,
    const float* __restrict__ W, const float* __restrict__ bias,
    u16* __restrict__ Wh, u16* __restrict__ Wl, float* __restrict__ rb){
  __shared__ float scl[128], shf[128], stot[256], rred[256];
  fold_body(blockIdx.x, threadIdx.x, sums, bw, bb, W, bias, Wh, Wl, rb, scl, shf, stot, rred);
}

__global__ __launch_bounds__(256) void k_fold2(
    const float* __restrict__ sumsA, const float* __restrict__ bwA, const float* __restrict__ bbA,
    const float* __restrict__ WA, const float* __restrict__ biasA,
    u16* __restrict__ WhA, u16* __restrict__ WlA, float* __restrict__ rbA,
    const float* __restrict__ sumsB, const float* __restrict__ bwB, const float* __restrict__ bbB,
    const float* __restrict__ WB, const float* __restrict__ biasB,
    u16* __restrict__ WhB, u16* __restrict__ WlB, float* __restrict__ rbB){
  __shared__ float scl[128], shf[128], stot[256], rred[256];
  int bb_ = blockIdx.x;
  if (bb_ < 8)
    fold_body(bb_, threadIdx.x, sumsA, bwA, bbA, WA, biasA, WhA, WlA, rbA, scl, shf, stot, rred);
  else
    fold_body(bb_ - 8, threadIdx.x, sumsB, bwB, bbB, WB, biasB, WhB, WlB, rbB, scl, shf, stot, rred);
}

// ---------------- epilogue macro: bias + rank-one + relu + store + slotted stats ----------------
#define CONV_EPILOGUE(RB, HOUT, SOUT, BLK)                                     \
  __syncthreads();                                                             \
  sred[t] = 0.f;                                                               \
  __syncthreads();                                                             \
  _Pragma("unroll")                                                            \
  for (int nt = 0; nt < 8; nt++){                                              \
    int colc = nt * 16 + m;                                                    \
    float rv = RB[colc], bv = RB[128 + colc];                                  \
    float s = 0.f, qq = 0.f;                                                   \
    _Pragma("unroll")                                                          \
    for (int r = 0; r < 4; r++){                                               \
      int rown = row0 + q * 4 + r;                                             \
      float v = C[nt][r] + srow[rown] * rv + bv;                               \
      v = fmaxf(v, 0.f);                                                       \
      u16 sv = f2bf(v);                                                        \
      HOUT[(size_t)rown * 128 + colc] = sv;                                    \
      if (rown < N_NODES){ float vv = bf2f(sv); s += vv; qq += vv * vv; }      \
    }                                                                          \
    s  += __shfl_xor(s, 16, 64);  s  += __shfl_xor(s, 32, 64);                 \
    qq += __shfl_xor(qq, 16, 64); qq += __shfl_xor(qq, 32, 64);                \
    if (q == 0){                                                               \
      atomicAdd(&sred[colc], s);                                               \
      atomicAdd(&sred[128 + colc], qq);                                        \
    }                                                                          \
  }                                                                            \
  __syncthreads();                                                             \
  atomicAdd(&SOUT[((BLK) & (NSLOT - 1)) * 256 + t], sred[t]);

#define FMA_KS(KS, V, WT) \
  acc[KS][0] += (WT) * __uint_as_float((V).x << 16); acc[KS][1] += (WT) * __uint_as_float((V).x & 0xffff0000u); \
  acc[KS][2] += (WT) * __uint_as_float((V).y << 16); acc[KS][3] += (WT) * __uint_as_float((V).y & 0xffff0000u); \
  acc[KS][4] += (WT) * __uint_as_float((V).z << 16); acc[KS][5] += (WT) * __uint_as_float((V).z & 0xffff0000u); \
  acc[KS][6] += (WT) * __uint_as_float((V).w << 16); acc[KS][7] += (WT) * __uint_as_float((V).w & 0xffff0000u);

#define VMCNT6() asm volatile("s_waitcnt vmcnt(6)" ::: "memory")
#define VMCNT5() asm volatile("s_waitcnt vmcnt(5)" ::: "memory")
#define SB0()    __builtin_amdgcn_sched_barrier(0)

// ---------------- LDS-staged gather: global_load_lds double-buffer, counted vmcnt ----------------
// (proven round-5 schedule: 2 stages x 4KB, vmcnt(6)/(5), 4-reg adj rotation, granularity-2 tail)
__device__ __forceinline__ void gll_stage(const u16* __restrict__ h, u16* dst, int2 aj, int lane){
  int c = lane & 15, g = lane >> 4;
  #pragma unroll
  for (int ii = 0; ii < 4; ii++){
    int rl = ii * 4 + g;
    int srcrow = __shfl(aj.x, rl, 64);
    const u16* src = h + (size_t)srcrow * 128 + (size_t)((c ^ rl) * 8);
    __builtin_amdgcn_global_load_lds((const void*)src, (void*)(dst + ii * 512), 16, 0, 0);
  }
}

#define GITER(WA, WB, WC, WD, STG, J)                                          \
  WD = *(const int2*)(adj + base_ + min((J) + 3, dcl));                        \
  VMCNT6();                                                                    \
  {                                                                            \
    float wgt = __int_as_float(__shfl((WA).y, m, 64));                         \
    if ((J) < deg){                                                            \
      const u16* sp = stage + (STG) * 2048;                                    \
      _Pragma("unroll")                                                        \
      for (int ks = 0; ks < 4; ks++){                                          \
        int slot = (q + 4 * ks) ^ m;                                           \
        uint4 v = *(const uint4*)(sp + m * 128 + slot * 8);                    \
        FMA_KS(ks, v, wgt)                                                     \
      }                                                                        \
    }                                                                          \
  }                                                                            \
  VMCNT5();                                                                    \
  gll_stage(h, stage + (STG) * 2048, WC, lane);                                \
  SB0();

__device__ __forceinline__ void gather_row_lds(const u16* __restrict__ h,
    const int* __restrict__ ptrA, const int2* __restrict__ adj,
    const float* __restrict__ dinv, int row0, int lane, u16* stage,
    float (&acc)[4][8]){
  int m = lane & 15, q = lane >> 4;
  #pragma unroll
  for (int ks = 0; ks < 4; ks++)
    #pragma unroll
    for (int j = 0; j < 8; j++) acc[ks][j] = 0.f;
  int r = row0 + m;
  int r2 = min(r, N_NODES - 1);
  int b0 = ptrA[r2], b1 = ptrA[r2 + 1];
  int deg = (r < N_NODES) ? (b1 - b0) : 0;
  int base_ = min(b0, NEDGE - 1);
  int dcl = max(deg - 1, 0);
  float di = dinv[r2];
  float sw = (r < N_NODES) ? di * di : 0.f;
  // self-loop (registers; unconditional clamped loads)
  const u16* hq = h + q * 8;
  const u16* sp_ = hq + (size_t)r2 * 128;
  uint4 s0 = *(const uint4*)(sp_);
  uint4 s1 = *(const uint4*)(sp_ + 32);
  uint4 s2 = *(const uint4*)(sp_ + 64);
  uint4 s3 = *(const uint4*)(sp_ + 96);
  int2 W0 = *(const int2*)(adj + base_);
  int2 W1 = *(const int2*)(adj + base_ + min(1, dcl));
  // wave-max degree (uniform over wave)
  int wmax = deg;
  wmax = max(wmax, __shfl_xor(wmax, 1, 64));
  wmax = max(wmax, __shfl_xor(wmax, 2, 64));
  wmax = max(wmax, __shfl_xor(wmax, 4, 64));
  wmax = max(wmax, __shfl_xor(wmax, 8, 64));
  FMA_KS(0, s0, sw) FMA_KS(1, s1, sw) FMA_KS(2, s2, sw) FMA_KS(3, s3, sw)
  if (wmax > 0){
    int2 W2 = W0, W3 = W0;
    SB0();
    gll_stage(h, stage, W0, lane);          // edge 0 -> stage 0
    SB0();
    W2 = *(const int2*)(adj + base_ + min(2, dcl));
    SB0();
    gll_stage(h, stage + 2048, W1, lane);   // edge 1 -> stage 1
    SB0();
    int j0 = 0;
    for (;;){
      GITER(W0, W1, W2, W3, 0, j0)
      GITER(W1, W2, W3, W0, 1, j0 + 1)
      j0 += 2; if (j0 >= wmax) break;
      GITER(W2, W3, W0, W1, 0, j0)
      GITER(W3, W0, W1, W2, 1, j0 + 1)
      j0 += 2; if (j0 >= wmax) break;
    }
  }
}

#define BUILD_AFRAG()                                                          \
  bf16x8 AH[4], AL[4];                                                         \
  _Pragma("unroll")                                                            \
  for (int ks = 0; ks < 4; ks++)                                               \
    _Pragma("unroll")                                                          \
    for (int j = 0; j < 8; j++){                                               \
      u16 hh = f2bf(acc[ks][j]);                                               \
      AH[ks][j] = (short)hh;                                                   \
      AL[ks][j] = (short)f2bf(acc[ks][j] - bf2f(hh));                          \
    }

#define MFMA_3PASS(WH, WL_)                                                    \
  _Pragma("unroll")                                                            \
  for (int ks = 0; ks < 4; ks++){                                              \
    _Pragma("unroll")                                                          \
    for (int nt = 0; nt < 8; nt++){                                            \
      bf16x8 bh = ((const bf16x8*)WH)[(nt * 4 + ks) * 64 + lane];              \
      bf16x8 bl = ((const bf16x8*)WL_)[(nt * 4 + ks) * 64 + lane];             \
      C[nt] = __builtin_amdgcn_mfma_f32_16x16x32_bf16(AH[ks], bh, C[nt], 0, 0, 0); \
      C[nt] = __builtin_amdgcn_mfma_f32_16x16x32_bf16(AL[ks], bh, C[nt], 0, 0, 0); \
      C[nt] = __builtin_amdgcn_mfma_f32_16x16x32_bf16(AH[ks], bl, C[nt], 0, 0, 0); \
    }                                                                          \
  }

// ---------------- fused conv: LDS-staged gather + MFMA (b-frags from global) + stats ----------------
__global__ __launch_bounds__(256, 4) void k_conv(
    const u16* __restrict__ h, const int* __restrict__ ptrA, const int2* __restrict__ adj,
    const float* __restrict__ dinv, const float* __restrict__ srow,
    const u16* __restrict__ Wh, const u16* __restrict__ Wl, const float* __restrict__ rb,
    u16* __restrict__ hout, float* __restrict__ sums_out){
  __shared__ u16 hstage[4][2][2048];
  __shared__ float sred[256];
  int t = threadIdx.x;
  int wave = t >> 6, lane = t & 63, m = lane & 15, q = lane >> 4;
  int blk = blockIdx.x;
  int row0 = blk * 64 + wave * 16;
  float acc[4][8];
  gather_row_lds(h, ptrA, adj, dinv, row0, lane, &hstage[wave][0][0], acc);
  BUILD_AFRAG()
  f32x4 C[8];
  #pragma unroll
  for (int nt = 0; nt < 8; nt++) C[nt] = f32x4{0.f, 0.f, 0.f, 0.f};
  MFMA_3PASS(Wh, Wl)
  CONV_EPILOGUE(rb, hout, sums_out, blk)
}

// ---------------- paired conv: two independent convs in one launch (grid 2*NBLK) ----------------
__global__ __launch_bounds__(256, 4) void k_conv2(
    const u16* __restrict__ hA, const u16* __restrict__ hB,
    const int* __restrict__ ptrA, const int2* __restrict__ adj,
    const float* __restrict__ dinv, const float* __restrict__ srow,
    const u16* __restrict__ WhA, const u16* __restrict__ WlA, const float* __restrict__ rbA,
    u16* __restrict__ houtA, float* __restrict__ sumsA,
    const u16* __restrict__ WhB, const u16* __restrict__ WlB, const float* __restrict__ rbB,
    u16* __restrict__ houtB, float* __restrict__ sumsB){
  __shared__ u16 hstage[4][2][2048];
  __shared__ float sred[256];
  int t = threadIdx.x;
  int wave = t >> 6, lane = t & 63, m = lane & 15, q = lane >> 4;
  int bb = blockIdx.x;
  int second = bb >= NBLK;
  int blk = second ? bb - NBLK : bb;
  const u16* h = second ? hB : hA;
  const u16* Wh = second ? WhB : WhA;
  const u16* Wl = second ? WlB : WlA;
  const float* rb = second ? rbB : rbA;
  u16* hout = second ? houtB : houtA;
  float* sums_out = second ? sumsB : sumsA;
  int row0 = blk * 64 + wave * 16;
  float acc[4][8];
  gather_row_lds(h, ptrA, adj, dinv, row0, lane, &hstage[wave][0][0], acc);
  BUILD_AFRAG()
  f32x4 C[8];
  #pragma unroll
  for (int nt = 0; nt < 8; nt++) C[nt] = f32x4{0.f, 0.f, 0.f, 0.f};
  MFMA_3PASS(Wh, Wl)
  CONV_EPILOGUE(rb, hout, sums_out, blk)
}

// ---------------- dual conv: one gather, two folded-W phases (a2 & c2 share S@a1) ----------------
__global__ __launch_bounds__(256, 4) void k_dualconv(
    const u16* __restrict__ h, const int* __restrict__ ptrA, const int2* __restrict__ adj,
    const float* __restrict__ dinv, const float* __restrict__ srow,
    const u16* __restrict__ Wh1, const u16* __restrict__ Wl1, const float* __restrict__ rb1,
    u16* __restrict__ hout1, float* __restrict__ sums1,
    const u16* __restrict__ Wh2, const u16* __restrict__ Wl2, const float* __restrict__ rb2,
    u16* __restrict__ hout2, float* __restrict__ sums2){
  __shared__ u16 hstage[4][2][2048];
  __shared__ float sred[256];
  int t = threadIdx.x;
  int wave = t >> 6, lane = t & 63, m = lane & 15, q = lane >> 4;
  int blk = blockIdx.x;
  int row0 = blk * 64 + wave * 16;
  float acc[4][8];
  gather_row_lds(h, ptrA, adj, dinv, row0, lane, &hstage[wave][0][0], acc);
  BUILD_AFRAG()
  f32x4 C[8];
  #pragma unroll
  for (int nt = 0; nt < 8; nt++) C[nt] = f32x4{0.f, 0.f, 0.f, 0.f};
  MFMA_3PASS(Wh1, Wl1)
  CONV_EPILOGUE(rb1, hout1, sums1, blk)
  #pragma unroll
  for (int nt = 0; nt < 8; nt++) C[nt] = f32x4{0.f, 0.f, 0.f, 0.f};
  MFMA_3PASS(Wh2, Wl2)
  CONV_EPILOGUE(rb2, hout2, sums2, blk)
}

// ---------------- branch-4 elementwise: out = relu(bn(h)); slotted stats (uint2 = 8B/lane) ----------------
__global__ __launch_bounds__(256) void k_normrelu(const u16* __restrict__ h, const float* __restrict__ sums,
    const float* __restrict__ bw, const float* __restrict__ bb, u16* __restrict__ o,
    float* __restrict__ sums_out){
  __shared__ float scl[128], shf[128], R[2048], stot[256];
  int t = threadIdx.x;
  {
    float s = 0.f;
    #pragma unroll 4
    for (int sl = 0; sl < NSLOT; sl++) s += sums[sl * 256 + t];
    stot[t] = s;
  }
  __syncthreads();
  if (t < 128){
    float mu  = stot[t] * (1.f / N_NODES);
    float var = stot[128 + t] * (1.f / N_NODES) - mu * mu;
    float sc  = bw[t] * rsqrtf(var + EPS);
    scl[t] = sc; shf[t] = bb[t] - mu * sc;
  }
  __syncthreads();
  int c0 = (t & 31) * 4;
  float sc0 = scl[c0], sh0 = shf[c0], sc1 = scl[c0 + 1], sh1 = shf[c0 + 1];
  float sc2 = scl[c0 + 2], sh2 = shf[c0 + 2], sc3 = scl[c0 + 3], sh3 = shf[c0 + 3];
  float s0 = 0.f, q0 = 0.f, s1 = 0.f, q1 = 0.f, s2 = 0.f, q2 = 0.f, s3 = 0.f, q3 = 0.f;
  size_t base = (size_t)blockIdx.x * 2048 + t;
  #pragma unroll
  for (int it = 0; it < 8; it++){
    size_t idx = base + (size_t)it * 256;
    if (idx < (size_t)N_NODES * 32){
      uint2 v = ((const uint2*)h)[idx];
      float x0 = fmaxf(bf2f(v.x & 0xffffu) * sc0 + sh0, 0.f);
      float x1 = fmaxf(bf2f(v.x >> 16) * sc1 + sh1, 0.f);
      float x2 = fmaxf(bf2f(v.y & 0xffffu) * sc2 + sh2, 0.f);
      float x3 = fmaxf(bf2f(v.y >> 16) * sc3 + sh3, 0.f);
      u16 r0 = f2bf(x0), r1 = f2bf(x1), r2 = f2bf(x2), r3 = f2bf(x3);
      uint2 w;
      w.x = (u32)r0 | ((u32)r1 << 16);
      w.y = (u32)r2 | ((u32)r3 << 16);
      ((uint2*)o)[idx] = w;
      float y0 = bf2f(r0), y1 = bf2f(r1), y2 = bf2f(r2), y3 = bf2f(r3);
      s0 += y0; q0 += y0 * y0; s1 += y1; q1 += y1 * y1;
      s2 += y2; q2 += y2 * y2; s3 += y3; q3 += y3 * y3;
    }
  }
  R[t] = s0; R[256 + t] = s1; R[512 + t] = s2; R[768 + t] = s3;
  R[1024 + t] = q0; R[1280 + t] = q1; R[1536 + t] = q2; R[1792 + t] = q3;
  __syncthreads();
  if (t < 128){
    int j = t & 3, l = t >> 2;           // col t = l*4 + j handled by threads th: th&31==l
    float S = 0.f, Q = 0.f;
    #pragma unroll
    for (int g = 0; g < 8; g++){
      int th = l + 32 * g;
      S += R[j * 256 + th];
      Q += R[1024 + j * 256 + th];
    }
    float* so = sums_out + (blockIdx.x & (NSLOT - 1)) * 256;
    atomicAdd(&so[t], S);
    atomicAdd(&so[128 + t], Q);
  }
}

// ---------------- global_add_pool: uint4 16B/lane, shfl row-reduce ----------------
__global__ __launch_bounds__(128) void k_pool(const u16* __restrict__ h, const int* __restrict__ gptr,
                                              float* __restrict__ gdst){
  __shared__ float part[2][16][8];
  int g = blockIdx.x >> 3, s = blockIdx.x & 7, t = threadIdx.x;
  int cc = t & 15, rr = t >> 4, wv = t >> 6, rrw = rr & 3;
  int b = gptr[g], e = gptr[g + 1];
  int len = e - b, per = (len + 7) >> 3;
  int r0 = b + s * per, r1 = min(r0 + per, e);
  float a[8] = {0.f, 0.f, 0.f, 0.f, 0.f, 0.f, 0.f, 0.f};
  for (int r = r0 + rr; r < r1; r += 8){
    uint4 v = *(const uint4*)(h + (size_t)r * 128 + cc * 8);
    a[0] += bf2f(v.x & 0xffffu); a[1] += bf2f(v.x >> 16);
    a[2] += bf2f(v.y & 0xffffu); a[3] += bf2f(v.y >> 16);
    a[4] += bf2f(v.z & 0xffffu); a[5] += bf2f(v.z >> 16);
    a[6] += bf2f(v.w & 0xffffu); a[7] += bf2f(v.w >> 16);
  }
  #pragma unroll
  for (int j = 0; j < 8; j++){
    a[j] += __shfl_xor(a[j], 16, 64);
    a[j] += __shfl_xor(a[j], 32, 64);
  }
  if (rrw == 0){
    #pragma unroll
    for (int j = 0; j < 8; j++) part[wv][cc][j] = a[j];
  }
  __syncthreads();
  {
    float sum = part[0][t >> 3][t & 7] + part[1][t >> 3][t & 7];
    atomicAdd(&gdst[g * 128 + t], sum);
  }
}

// ---------------- head: 8x8 register-tile FC, shfl-reduced classifier ----------------
__global__ __launch_bounds__(256) void k_head(const float* __restrict__ gbuf,
    const float* __restrict__ fcw, const float* __restrict__ fcb,
    const float* __restrict__ Wfc, const float* __restrict__ bfc,
    const float* __restrict__ bhw, const float* __restrict__ bhb,
    const float* __restrict__ Wcl, const float* __restrict__ bcl,
    float* __restrict__ out){
  __shared__ float GS[128 * 65];           // Gbn k-half staging (33 KB)
  __shared__ float ls[256], lq[256];
  __shared__ float scl[128], shf[128], scl2[128], shf2[128];
  __shared__ float sumT[128], sumQ[128];
  __shared__ float WclT[1280], Lrow[1280];
  int t = threadIdx.x, br = blockIdx.x;
  int slot = (br == 1) ? 1 : (br == 3 ? 3 : 0);   // branch3 == branch1 (slot 0)
  const float* G = gbuf + slot * 16384;
  { // stats of G
    int col = t & 127, hf2 = t >> 7;
    float s = 0.f, q = 0.f;
    for (int g = hf2 * 64; g < hf2 * 64 + 64; g++){ float v = G[g * 128 + col]; s += v; q += v * v; }
    ls[t] = s; lq[t] = q;
  }
  for (int idx = t; idx < 1280; idx += 256){     // WclT[cc][c] = Wcl[c][cc]
    int cc = idx >> 7, c = idx & 127;
    WclT[idx] = Wcl[c * 10 + cc];
  }
  if (t < 128){ sumT[t] = 0.f; sumQ[t] = 0.f; }
  __syncthreads();
  if (t < 128){
    float s = ls[t] + ls[t + 128], q = lq[t] + lq[t + 128];
    float mu = s * (1.f / 128), var = q * (1.f / 128) - mu * mu;
    float sc = fcw[t] * rsqrtf(var + EPS);
    scl[t] = sc; shf[t] = fcb[t] - mu * sc;
  }
  __syncthreads();
  int tr = t >> 4, tc = t & 15, r0 = tr * 8, c0 = tc * 8;
  float acc[8][8];
  #pragma unroll
  for (int a = 0; a < 8; a++)
    #pragma unroll
    for (int b = 0; b < 8; b++) acc[a][b] = 0.f;
  for (int kh = 0; kh < 2; kh++){
    for (int idx = t; idx < 8192; idx += 256){
      int r = idx >> 6, kk = idx & 63, f = kh * 64 + kk;
      GS[r * 65 + kk] = G[r * 128 + f] * scl[f] + shf[f];
    }
    __syncthreads();
    #pragma unroll 2
    for (int k = 0; k < 64; k++){
      float a[8];
      #pragma unroll
      for (int ri = 0; ri < 8; ri++) a[ri] = GS[(r0 + ri) * 65 + k];
      float4 b0 = *(const float4*)&Wfc[(kh * 64 + k) * 128 + c0];
      float4 b1 = *(const float4*)&Wfc[(kh * 64 + k) * 128 + c0 + 4];
      float bb[8] = {b0.x, b0.y, b0.z, b0.w, b1.x, b1.y, b1.z, b1.w};
      #pragma unroll
      for (int ri = 0; ri < 8; ri++)
        #pragma unroll
        for (int ci = 0; ci < 8; ci++) acc[ri][ci] += a[ri] * bb[ci];
    }
    __syncthreads();
  }
  #pragma unroll
  for (int ci = 0; ci < 8; ci++){
    float bb = bfc[c0 + ci];
    float s = 0.f, q = 0.f;
    #pragma unroll
    for (int ri = 0; ri < 8; ri++){
      float v = fmaxf(acc[ri][ci] + bb, 0.f);
      acc[ri][ci] = v; s += v; q += v * v;
    }
    atomicAdd(&sumT[c0 + ci], s);
    atomicAdd(&sumQ[c0 + ci], q);
  }
  __syncthreads();
  if (t < 128){
    float mu = sumT[t] * (1.f / 128), var = sumQ[t] * (1.f / 128) - mu * mu;
    float sc = bhw[t] * rsqrtf(var + EPS);
    scl2[t] = sc; shf2[t] = bhb[t] - mu * sc;
  }
  __syncthreads();
  #pragma unroll
  for (int ci = 0; ci < 8; ci++){
    float sc = scl2[c0 + ci], sh = shf2[c0 + ci];
    #pragma unroll
    for (int ri = 0; ri < 8; ri++) acc[ri][ci] = acc[ri][ci] * sc + sh;
  }
  #pragma unroll
  for (int ri = 0; ri < 8; ri++){
    float pl[10];
    #pragma unroll
    for (int cc = 0; cc < 10; cc++) pl[cc] = 0.f;
    #pragma unroll
    for (int ci = 0; ci < 8; ci++){
      float v = acc[ri][ci];
      #pragma unroll
      for (int cc = 0; cc < 10; cc++) pl[cc] += v * WclT[cc * 128 + c0 + ci];
    }
    #pragma unroll
    for (int msk = 1; msk < 16; msk <<= 1)
      #pragma unroll
      for (int cc = 0; cc < 10; cc++) pl[cc] += __shfl_xor(pl[cc], msk, 64);
    if (tc == 0)
      #pragma unroll
      for (int cc = 0; cc < 10; cc++) Lrow[(r0 + ri) * 10 + cc] = pl[cc];
  }
  __syncthreads();
  if (t < 128){
    float l[10];
    #pragma unroll
    for (int cc = 0; cc < 10; cc++) l[cc] = Lrow[t * 10 + cc] + bcl[cc];
    float m = l[0];
    #pragma unroll
    for (int cc = 1; cc < 10; cc++) m = fmaxf(m, l[cc]);
    float se = 0.f;
    #pragma unroll
    for (int cc = 0; cc < 10; cc++) se += expf(l[cc] - m);
    float lse = m + logf(se);
    #pragma unroll
    for (int cc = 0; cc < 10; cc++) out[br * 1280 + t * 10 + cc] = l[cc] - lse;
  }
}

extern "C" void kernel_launch(void* const* d_in, const int* in_sizes, int n_in,
                              void* d_out, int out_size, void* d_ws, size_t ws_size,
                              hipStream_t stream){
  const float* x    = (const float*)d_in[0];
  const int*  ei    = (const int*)d_in[1];      // [2,E]: rows then cols
  const int*  batch = (const int*)d_in[2];
  const float* ew   = (const float*)d_in[3];
  const float* bnfw = (const float*)d_in[4];
  const float* bnfb = (const float*)d_in[5];
  const float* cfW  = (const float*)d_in[6];
  const float* cfb  = (const float*)d_in[7];
  const float* bnsw = (const float*)d_in[8];
  const float* bnsb = (const float*)d_in[9];
  const float* cvW  = (const float*)d_in[10];
  const float* cvb  = (const float*)d_in[11];
  const float* fcw  = (const float*)d_in[12];
  const float* fcb  = (const float*)d_in[13];
  const float* Wfc  = (const float*)d_in[14];
  const float* bfc  = (const float*)d_in[15];
  const float* bhw  = (const float*)d_in[16];
  const float* bhb  = (const float*)d_in[17];
  const float* Wcl  = (const float*)d_in[18];
  const float* bcl  = (const float*)d_in[19];
  float* out = (float*)d_out;

  char* p = (char*)d_ws;
  auto carve = [&](size_t bytes)->void*{ void* r = (void*)p; p += (bytes + 255) & ~(size_t)255; return r; };
  float* deg  = (float*)carve((size_t)NPAD * 4);
  float* dinv = (float*)carve((size_t)NPAD * 4);
  float* srow = (float*)carve((size_t)NPAD * 4);
  int*   cnt  = (int*)carve((size_t)NPAD * 4);
  int*   fill = (int*)carve((size_t)NPAD * 4);
  int*   ptrA = (int*)carve((size_t)(NPAD + 1) * 4);
  int*   bpart= (int*)carve((size_t)391 * 128 * 4);
  int*   csum = (int*)carve(512);
  int*   coff = (int*)carve(512);
  int*   gptr = (int*)carve(1024);
  float* S    = (float*)carve((size_t)13 * NSLOT * 1024);   // 13 steps x NSLOT x 256 floats
  float* gbuf = (float*)carve(4 * 128 * 128 * 4);
  u16*   F0h  = (u16*)carve(32768);  u16* F0l = (u16*)carve(32768);  float* F0r = (float*)carve(1024);
  u16*   F1h  = (u16*)carve(32768);  u16* F1l = (u16*)carve(32768);  float* F1r = (float*)carve(1024);
  u16*   F2h  = (u16*)carve(32768);  u16* F2l = (u16*)carve(32768);  float* F2r = (float*)carve(1024);
  u16*   B0   = (u16*)carve((size_t)NPAD * 256);
  u16*   B1   = (u16*)carve((size_t)NPAD * 256);
  u16*   B2   = (u16*)carve((size_t)NPAD * 256);
  u16*   B3   = (u16*)carve((size_t)NPAD * 256);
  int2*  adj  = (int2*)carve((size_t)NEDGE * 8);
  u16*   Xb   = B3;   // bf16 x staging; B3's first real write (d2) is after L0 conv consumes Xb
  auto Sb = [&](int i){ return S + (size_t)i * NSLOT * 256; };

  (void)hipMemsetAsync(S, 0, (size_t)13 * NSLOT * 1024, stream);

  // preprocessing: degrees, norms, CSR, group offsets
  k_init<<<392, 256, 0, stream>>>(deg, cnt, fill, gbuf);
  k_deg<<<3125, 256, 0, stream>>>(ei + NEDGE, ew, deg, cnt);
  k_dinv<<<391, 256, 0, stream>>>(deg, dinv, srow);
  k_chunksum<<<98, 256, 0, stream>>>(cnt, csum);
  k_chunkscan<<<1, 128, 0, stream>>>(csum, coff, ptrA);
  k_scan2<<<98, 256, 0, stream>>>(cnt, coff, ptrA);
  k_fill<<<3125, 256, 0, stream>>>(ei, ei + NEDGE, ew, dinv, ptrA, fill, adj, srow);
  k_bhist<<<391, 256, 0, stream>>>(batch, bpart);
  k_bscan<<<1, 128, 0, stream>>>(bpart, gptr);
  k_cvtstats<<<NBLK, 256, 0, stream>>>(x, (u32*)Xb, Sb(0));

  auto fold = [&](const float* Sin, const float* bw, const float* bb,
                  const float* W, const float* bias, u16* Fh, u16* Fl, float* Fr){
    k_fold<<<8, 256, 0, stream>>>(Sin, bw, bb, W, bias, Fh, Fl, Fr);
  };
  auto conv = [&](const u16* hin, const u16* Fh, const u16* Fl, const float* Fr,
                  u16* hout, float* Sout){
    k_conv<<<NBLK, 256, 0, stream>>>(hin, ptrA, adj, dinv, srow, Fh, Fl, Fr, hout, Sout);
  };

  // L0: h_init = relu(conv(bn_feat(x)))
  fold(Sb(0), bnfw, bnfb, cfW, cfb, F0h, F0l, F0r);
  conv(Xb, F0h, F0l, F0r, B0, Sb(1));                                         // B0 = h_init
  // a1 = step(h_init, bn0/W0)  (== branch2 c1)
  fold(Sb(1), bnsw, bnsb, cvW, cvb, F1h, F1l, F1r);
  conv(B0, F1h, F1l, F1r, B1, Sb(2));                                         // B1 = a1
  // branch 4: d1,d2,d3 (d1 uses stats(h_init))
  k_normrelu<<<NBLK, 256, 0, stream>>>(B0, Sb(1), bnsw,       bnsb,       B2, Sb(3));   // d1 -> B2
  k_normrelu<<<NBLK, 256, 0, stream>>>(B2, Sb(3), bnsw + 128, bnsb + 128, B3, Sb(4));   // d2 -> B3
  k_normrelu<<<NBLK, 256, 0, stream>>>(B3, Sb(4), bnsw + 256, bnsb + 256, B2, Sb(12));  // d3 -> B2
  k_pool<<<1024, 128, 0, stream>>>(B2, gptr, gbuf + 3 * 16384);
  // dual: a2 = step(a1, bn1/W1), c2 = step(a1, bn0/W0) — one gather of S@a1; both folds one launch
  k_fold2<<<16, 256, 0, stream>>>(
      Sb(2), bnsw + 128, bnsb + 128, cvW + 16384, cvb + 128, F0h, F0l, F0r,
      Sb(2), bnsw,       bnsb,       cvW,         cvb,       F1h, F1l, F1r);
  k_dualconv<<<NBLK, 256, 0, stream>>>(B1, ptrA, adj, dinv, srow,
      F0h, F0l, F0r, B3, Sb(5),       // a2 -> B3
      F1h, F1l, F1r, B2, Sb(6));      // c2 -> B2
  // a3 = step(a2, bn2/W2) -> branches 1 & 3 ; c3 = step(c2, bn1/W1) — independent, one launch
  k_fold2<<<16, 256, 0, stream>>>(
      Sb(5), bnsw + 256, bnsb + 256, cvW + 32768, cvb + 256, F2h, F2l, F2r,
      Sb(6), bnsw + 128, bnsb + 128, cvW + 16384, cvb + 128, F0h, F0l, F0r);
  k_conv2<<<2 * NBLK, 256, 0, stream>>>(B3, B2, ptrA, adj, dinv, srow,
      F2h, F2l, F2r, B0, Sb(10),      // a3 -> B0
      F0h, F0l, F0r, B1, Sb(7));      // c3 -> B1
  k_pool<<<1024, 128, 0, stream>>>(B0, gptr, gbuf);
  // c4 = step(c3, bn1/W1)
  fold(Sb(7), bnsw + 128, bnsb + 128, cvW + 16384, cvb + 128, F1h, F1l, F1r);
  conv(B1, F1h, F1l, F1r, B2, Sb(8));                                         // c4 -> B2
  // c5 = step(c4, bn2/W2)
  fold(Sb(8), bnsw + 256, bnsb + 256, cvW + 32768, cvb + 256, F2h, F2l, F2r);
  conv(B2, F2h, F2l, F2r, B1, Sb(9));                                         // c5 -> B1
  // c6 = step(c5, bn2/W2) -> branch 2
  fold(Sb(9), bnsw + 256, bnsb + 256, cvW + 32768, cvb + 256, F0h, F0l, F0r);
  conv(B1, F0h, F0l, F0r, B3, Sb(11));                                        // c6 -> B3
  k_pool<<<1024, 128, 0, stream>>>(B3, gptr, gbuf + 16384);

  k_head<<<4, 256, 0, stream>>>(gbuf, fcw, fcb, Wfc, bfc, bhw, bhb, Wcl, bcl, out);
}